// Round 17
// baseline (124.209 us; speedup 1.0000x reference)
//
#include <hip/hip_runtime.h>
#include <hip/hip_bf16.h>

typedef unsigned short u16;
typedef unsigned int u32;
typedef __attribute__((ext_vector_type(8))) short bf16x8;
typedef __attribute__((ext_vector_type(4))) short bf16x4;
typedef __attribute__((ext_vector_type(4))) float f32x4;
typedef __attribute__((ext_vector_type(8))) u16 u16x8;
typedef __attribute__((ext_vector_type(4))) u16 u16x4;
typedef __attribute__((ext_vector_type(4))) u32 u32x4;

__device__ __forceinline__ u16 f2bf(float x){
  __hip_bfloat16 h = __float2bfloat16(x);
  return __builtin_bit_cast(u16, h);
}
__device__ __forceinline__ float bf2f(u16 u){
  __hip_bfloat16 h = __builtin_bit_cast(__hip_bfloat16, u);
  return __bfloat162float(h);
}

// ---------------- LayerNorm over rows of 512 (used for ln2 only) ----------------
template<bool BF>
__global__ __launch_bounds__(256) void ln_kernel(const float* __restrict__ in,
    const float* __restrict__ g, const float* __restrict__ b,
    float* __restrict__ outf, u16* __restrict__ outb)
{
  int row = blockIdx.x, tid = threadIdx.x;
  const float* p = in + (size_t)row*512 + tid*2;
  float v0 = p[0], v1 = p[1];
  float s = v0+v1, ss = v0*v0+v1*v1;
  #pragma unroll
  for (int o=1;o<64;o<<=1){ s += __shfl_xor(s,o); ss += __shfl_xor(ss,o); }
  __shared__ float rs[4], rss[4];
  if ((tid&63)==0){ rs[tid>>6]=s; rss[tid>>6]=ss; }
  __syncthreads();
  s = rs[0]+rs[1]+rs[2]+rs[3]; ss = rss[0]+rss[1]+rss[2]+rss[3];
  float mean = s*(1.f/512.f);
  float var  = ss*(1.f/512.f) - mean*mean;
  float rstd = 1.f/sqrtf(var + 1e-5f);
  int d = tid*2;
  float o0 = (v0-mean)*rstd*g[d]   + b[d];
  float o1 = (v1-mean)*rstd*g[d+1] + b[d+1];
  if (BF){
    outb[(size_t)row*512+d]   = f2bf(o0);
    outb[(size_t)row*512+d+1] = f2bf(o1);
  } else {
    outf[(size_t)row*512+d]   = o0;
    outf[(size_t)row*512+d+1] = o1;
  }
}

// ---------------- conv input gather (transposed, bf16) ----------------
__global__ __launch_bounds__(256) void xgT_kernel(const float* __restrict__ x1, u16* __restrict__ xgT)
{
  int h = blockIdx.x, tid = threadIdx.x;
  #pragma unroll
  for (int rep=0;rep<6;rep++){
    int k = rep*256 + tid;
    int i = k/3, kk = k - i*3;
    int pos = 2*h - 1 + kk;
    float v = (pos >= 0 && pos < 512) ? x1[(size_t)i*512 + pos] : 0.f;
    xgT[(size_t)h*1536 + k] = f2bf(v);
  }
}

// ---------------- transpose+convert body (shared tile passed in) ----------------
__device__ __forceinline__ void transcvt_body(float (*t)[33],
    const float* __restrict__ in, u16* __restrict__ out, int K, int N, int bx, int by)
{
  int nb = bx*32, kb = by*32;
  int tx = threadIdx.x & 31, ty = threadIdx.x >> 5;
  #pragma unroll
  for (int i=0;i<32;i+=8) t[ty+i][tx] = in[(size_t)(kb+ty+i)*N + nb+tx];
  __syncthreads();
  #pragma unroll
  for (int i=0;i<32;i+=8) out[(size_t)(nb+ty+i)*K + kb+tx] = f2bf(t[tx][ty+i]);
}

// ---------------- fused prep: ln1 + cvt_cached + wk/wc cvt + 3 weight transposes ----------------
__global__ __launch_bounds__(256) void prep_kernel(
    const float* __restrict__ x, const float* __restrict__ ln1g, const float* __restrict__ ln1b,
    const float* __restrict__ wk, const float* __restrict__ wc,
    const float* __restrict__ apw, const float* __restrict__ fcw, const float* __restrict__ pjw,
    const float* __restrict__ ck, const int* __restrict__ mask,
    float* __restrict__ x1,
    u16* __restrict__ wkcb, u16* __restrict__ apT, u16* __restrict__ fcT,
    u16* __restrict__ pjT, u16* __restrict__ kbf)
{
  __shared__ float t[32][33];
  __shared__ float rs[4], rss[4];
  int b = blockIdx.x, tid = threadIdx.x;
  if (b < 512){                       // ln1: x -> x1 (f32)
    const float* p = x + (size_t)b*512 + tid*2;
    float v0 = p[0], v1 = p[1];
    float s = v0+v1, ss = v0*v0+v1*v1;
    #pragma unroll
    for (int o=1;o<64;o<<=1){ s += __shfl_xor(s,o); ss += __shfl_xor(ss,o); }
    if ((tid&63)==0){ rs[tid>>6]=s; rss[tid>>6]=ss; }
    __syncthreads();
    s = rs[0]+rs[1]+rs[2]+rs[3]; ss = rss[0]+rss[1]+rss[2]+rss[3];
    float mean = s*(1.f/512.f);
    float var  = ss*(1.f/512.f) - mean*mean;
    float rstd = 1.f/sqrtf(var + 1e-5f);
    int d = tid*2;
    x1[(size_t)b*512+d]   = (v0-mean)*rstd*ln1g[d]   + ln1b[d];
    x1[(size_t)b*512+d+1] = (v1-mean)*rstd*ln1g[d+1] + ln1b[d+1];
  } else if (b < 8704){               // cached_k -> bf16 (skip masked t blocks)
    int flat = (b-512)*256 + tid;
    int row = flat >> 5, seg = flat & 31;
    if (mask[row>>9] == 0) return;
    const float* src = ck + (size_t)row*256 + seg*8;
    u16x8 o;
    #pragma unroll
    for (int j=0;j<8;j++) o[j] = f2bf(src[j]);
    *(u16x8*)(kbf + (size_t)row*256 + seg*8) = o;
  } else if (b < 9472){               // wk|wc -> wkcb (stacked 1024x1536)
    size_t i = (size_t)((b-8704)*256 + tid)*8;
    const size_t half = (size_t)512*1536;
    const float* src = (i < half) ? (wk + i) : (wc + (i - half));
    u16x8 o;
    #pragma unroll
    for (int j=0;j<8;j++) o[j] = f2bf(src[j]);
    *(u16x8*)(wkcb + i) = o;
  } else if (b < 9600){               // apw f32[256][512] -> apT bf16[512][256]
    int f = b - 9472;
    transcvt_body(t, apw, apT, 256, 512, f & 15, f >> 4);
  } else if (b < 10624){              // fcw f32[512][2048] -> fcT bf16[2048][512]
    int f = b - 9600;
    transcvt_body(t, fcw, fcT, 512, 2048, f & 63, f >> 6);
  } else {                            // pjw f32[2048][512] -> pjT bf16[512][2048]
    int f = b - 10624;                // 1024 tiles: bx 0..15, by 0..63
    transcvt_body(t, pjw, pjT, 2048, 512, f & 15, f >> 4);
  }
}

// ---------------- bf16 MFMA GEMM, W-wave K-split: 32x32 tile ----------------
template<int ACT, bool WF32, bool WBF, int W>
__global__ __launch_bounds__(64*W) void gemm4(
    const u16* __restrict__ A, const u16* __restrict__ B,
    const float* __restrict__ bias, const float* __restrict__ resid,
    float* __restrict__ outF, u16* __restrict__ outB, u16* __restrict__ outB2,
    int rowSplit, int M, int N, int K)
{
  __shared__ float red[W][32][33];
  int tid = threadIdx.x;
  int w = tid >> 6, lane = tid & 63;
  int lq = lane & 15, lg = lane >> 4;
  int m0 = blockIdx.y*32, n0 = blockIdx.x*32;
  int Ks = K / W;
  int kbeg = w * Ks;
  f32x4 acc00={0,0,0,0}, acc01={0,0,0,0}, acc10={0,0,0,0}, acc11={0,0,0,0};
  const u16* pa0 = A + (size_t)(m0+lq)*K + kbeg + lg*8;
  const u16* pa1 = pa0 + (size_t)16*K;
  const u16* pb0 = B + (size_t)(n0+lq)*K + kbeg + lg*8;
  const u16* pb1 = pb0 + (size_t)16*K;
  #pragma unroll 2
  for (int k0=0;k0<Ks;k0+=32){
    bf16x8 a0 = *(const bf16x8*)(pa0+k0);
    bf16x8 a1 = *(const bf16x8*)(pa1+k0);
    bf16x8 b0 = *(const bf16x8*)(pb0+k0);
    bf16x8 b1 = *(const bf16x8*)(pb1+k0);
    acc00 = __builtin_amdgcn_mfma_f32_16x16x32_bf16(a0,b0,acc00,0,0,0);
    acc01 = __builtin_amdgcn_mfma_f32_16x16x32_bf16(a0,b1,acc01,0,0,0);
    acc10 = __builtin_amdgcn_mfma_f32_16x16x32_bf16(a1,b0,acc10,0,0,0);
    acc11 = __builtin_amdgcn_mfma_f32_16x16x32_bf16(a1,b1,acc11,0,0,0);
  }
  f32x4 accs[2][2] = {{acc00,acc01},{acc10,acc11}};
  #pragma unroll
  for (int mi=0;mi<2;mi++)
    #pragma unroll
    for (int ni=0;ni<2;ni++)
      #pragma unroll
      for (int r=0;r<4;r++)
        red[w][mi*16+lg*4+r][ni*16+lq] = accs[mi][ni][r];
  __syncthreads();
  #pragma unroll
  for (int rr=0;rr<16/W;rr++){
    int cell = rr*64*W + tid;        // 0..1023
    int row = cell >> 5, col = cell & 31;
    float v = 0.f;
    #pragma unroll
    for (int ww=0;ww<W;ww++) v += red[ww][row][col];
    int grow = m0 + row, gcol = n0 + col;
    if (bias)  v += bias[gcol];
    if (ACT==1) v = v/(1.f+__expf(-1.702f*v));
    if (resid) v += resid[(size_t)grow*N+gcol];
    if (WF32) outF[(size_t)grow*N+gcol] = v;
    if (WBF){
      if (grow < rowSplit) outB[(size_t)grow*N+gcol] = f2bf(v);
      else                 outB2[(size_t)(grow-rowSplit)*N+gcol] = f2bf(v);
    }
  }
}

// ---------------- flash attention (r13-verified core; FINE=512-key chunks for 2x waves) ----------------
// FINE=1: chunk = one t-block (512 keys), c in [0,130): c<128 cached (gate mask[c]),
//   c=128 conv, c=129 self; nt=16 uniform. grid 17 cgrp x 16 qt x 8 xcd = 2176.
// FINE=0: r13/r15 coarse path (1024-key chunks, 66 c, grid 1152).
// LDS per 32-key tile: elem(d,k)=(d>>4)*512+k*16+(d&15) (16KB), double-buffered,
// global_load_lds(16B) pre-swizzled src, counted vmcnt(8); PV k-perm + canonical tr_read
// + counted lgkm pipeline. XCD swizzle keeps same-c blocks on one XCD (FETCH -73%, r15).
template<int FINE>
__global__ __launch_bounds__(128) void attn_flash(
    const u16* __restrict__ qb, const u16* __restrict__ keys,
    const int* __restrict__ mask,
    u16* __restrict__ pO, float* __restrict__ pL)
{
  __shared__ u16 kv[2][8192];
  int tid = threadIdx.x;
  int w = tid >> 6, lane = tid & 63, lq = lane & 15, lg = lane >> 4;
  int bid = blockIdx.x;
  int c = ((bid >> 7) << 3) | (bid & 7);
  int qt = (bid >> 3) & 15;
  const u16* kp = keys;
  int kstart, off = 0, nt;
  if (FINE){
    if (c >= 130) return;
    nt = 16;
    if (c == 129){ kp = qb; kstart = 0; }
    else if (c == 128){ kstart = 65536; }
    else { if (mask[c] == 0) return; kstart = c*512; }
  } else {
    c = ((bid >> 7) << 3) | (bid & 7);
    qt = (bid >> 3) & 15;
    if (c >= 66) return;
    kstart = c * 1024; nt = 32;
    if (c == 65){ kp = qb; kstart = 0; nt = 16; }
    else if (c == 64){ kstart = 65536; nt = 16; }
    else {
      int m0 = mask[2*c], m1 = mask[2*c+1];
      if (!m0 && !m1) return;
      off = m0 ? 0 : 512;
      nt = ((m0 && m1) ? 32 : 16);
    }
  }
  int qbase = qt*32 + w*16;

  bf16x8 qf[8];
  {
    const u16* qrow = qb + (size_t)(qbase+lq)*256 + lg*8;
    #pragma unroll
    for (int s=0;s<8;s++) qf[s] = *(const bf16x8*)(qrow + s*32);
  }
  f32x4 o[16];
  #pragma unroll
  for (int i=0;i<16;i++) o[i] = (f32x4){0,0,0,0};
  float l_acc = 0.f;

  auto kv3 = (__attribute__((address_space(3))) char*)&kv[0][0];
  unsigned kvaddr0 = (unsigned)(unsigned long long)kv3;
  const char* gbase = (const char*)kp + (size_t)(kstart+off)*512;

  #define STAGE(i, b) { \
    const char* tb = gbase + (size_t)(i)*16384; \
    _Pragma("unroll") \
    for (int rep=0; rep<8; rep++){ \
      int slot = rep*128 + tid; \
      int goff = ((slot&63)>>1)*512 + ((slot>>6)*16 + (slot&1)*8)*2; \
      __builtin_amdgcn_global_load_lds( \
        (const __attribute__((address_space(1))) unsigned*)(tb + goff), \
        (__attribute__((address_space(3))) unsigned*)(kv3 + (b)*16384 + (rep*128 + (tid & ~63))*16), \
        16, 0, 0); \
    } }

  #define ISSUE8(T, ab) \
    asm volatile( \
      "ds_read_b64_tr_b16 %0, %8 offset:0\n\t" \
      "ds_read_b64_tr_b16 %1, %8 offset:512\n\t" \
      "ds_read_b64_tr_b16 %2, %8 offset:1024\n\t" \
      "ds_read_b64_tr_b16 %3, %8 offset:1536\n\t" \
      "ds_read_b64_tr_b16 %4, %8 offset:2048\n\t" \
      "ds_read_b64_tr_b16 %5, %8 offset:2560\n\t" \
      "ds_read_b64_tr_b16 %6, %8 offset:3072\n\t" \
      "ds_read_b64_tr_b16 %7, %8 offset:3584\n\t" \
      : "=&v"(T[0]),"=&v"(T[1]),"=&v"(T[2]),"=&v"(T[3]), \
        "=&v"(T[4]),"=&v"(T[5]),"=&v"(T[6]),"=&v"(T[7]) \
      : "v"(ab) : "memory")

  #define MFMA4(T, base) { \
    bf16x8 v0_ = __builtin_shufflevector(T[0],T[1],0,1,2,3,4,5,6,7); \
    bf16x8 v1_ = __builtin_shufflevector(T[2],T[3],0,1,2,3,4,5,6,7); \
    bf16x8 v2_ = __builtin_shufflevector(T[4],T[5],0,1,2,3,4,5,6,7); \
    bf16x8 v3_ = __builtin_shufflevector(T[6],T[7],0,1,2,3,4,5,6,7); \
    o[(base)+0] = __builtin_amdgcn_mfma_f32_16x16x32_bf16(pa, v0_, o[(base)+0], 0,0,0); \
    o[(base)+1] = __builtin_amdgcn_mfma_f32_16x16x32_bf16(pa, v1_, o[(base)+1], 0,0,0); \
    o[(base)+2] = __builtin_amdgcn_mfma_f32_16x16x32_bf16(pa, v2_, o[(base)+2], 0,0,0); \
    o[(base)+3] = __builtin_amdgcn_mfma_f32_16x16x32_bf16(pa, v3_, o[(base)+3], 0,0,0); \
  }

  STAGE(0, 0);
  for (int i=0; i<nt; i++){
    int cur = i & 1;
    if (i+1 < nt){
      STAGE(i+1, cur^1);
      asm volatile("s_waitcnt vmcnt(8)" ::: "memory");
    } else {
      asm volatile("s_waitcnt vmcnt(0)" ::: "memory");
    }
    __syncthreads();

    // ---- QK^T (S^T = K * Q^T), A-frags as b128 from subtiled LDS ----
    const u16* kb = &kv[cur][0];
    f32x4 s0 = {0,0,0,0}, s1 = {0,0,0,0};
    #pragma unroll
    for (int s=0;s<8;s++){
      int e = (2*s + (lg>>1))*512 + lq*16 + (lg&1)*8;
      bf16x8 ka0 = *(const bf16x8*)(kb + e);
      bf16x8 ka1 = *(const bf16x8*)(kb + e + 256);
      s0 = __builtin_amdgcn_mfma_f32_16x16x32_bf16(ka0, qf[s], s0, 0,0,0);
      s1 = __builtin_amdgcn_mfma_f32_16x16x32_bf16(ka1, qf[s], s1, 0,0,0);
    }
    asm volatile("s_waitcnt lgkmcnt(0)" ::: "memory");

    // ---- PV tr_reads: issue two groups ahead, overlap exp/pack with latency ----
    unsigned trb = kvaddr0 + cur*16384 + lane*8;
    bf16x4 tA[8], tB[8], tC[8], tD[8];
    ISSUE8(tA, trb);
    ISSUE8(tB, trb + 4096);

    // ---- exp (no max); lane holds q=lq, keys {4lg+r} and {16+4lg+r} ----
    float p[8];
    #pragma unroll
    for (int r=0;r<4;r++){ p[r]   = __expf(s0[r]*0.0625f);
                           p[4+r] = __expf(s1[r]*0.0625f); }
    l_acc += (p[0]+p[1])+(p[2]+p[3])+((p[4]+p[5])+(p[6]+p[7]));
    // A-frag = own p values (k-perm: position j <-> key {4lg+j, 16+4lg+(j-4)})
    u32 w0 = (u32)f2bf(p[0]) | ((u32)f2bf(p[1])<<16);
    u32 w1 = (u32)f2bf(p[2]) | ((u32)f2bf(p[3])<<16);
    u32 w2 = (u32)f2bf(p[4]) | ((u32)f2bf(p[5])<<16);
    u32 w3 = (u32)f2bf(p[6]) | ((u32)f2bf(p[7])<<16);
    u32x4 fq = {w0,w1,w2,w3};
    bf16x8 pa = __builtin_bit_cast(bf16x8, fq);

    // ---- counted-wait pipeline ----
    asm volatile("s_waitcnt lgkmcnt(8)" ::: "memory");
    __builtin_amdgcn_sched_barrier(0);
    MFMA4(tA, 0);
    ISSUE8(tC, trb + 8192);
    asm volatile("s_waitcnt lgkmcnt(8)" ::: "memory");
    __builtin_amdgcn_sched_barrier(0);
    MFMA4(tB, 4);
    ISSUE8(tD, trb + 12288);
    asm volatile("s_waitcnt lgkmcnt(8)" ::: "memory");
    __builtin_amdgcn_sched_barrier(0);
    MFMA4(tC, 8);
    asm volatile("s_waitcnt lgkmcnt(0)" ::: "memory");
    __builtin_amdgcn_sched_barrier(0);
    MFMA4(tD, 12);
    __syncthreads();
  }
  #undef STAGE
  #undef ISSUE8
  #undef MFMA4

  l_acc += __shfl_xor(l_acc, 16);
  l_acc += __shfl_xor(l_acc, 32);
  size_t qrow = (size_t)c*512 + qbase;
  if (lane < 16) pL[qrow + lq] = l_acc;
  // o[dt][r] = O[q = 4lg+r][d = dt*16+lq]
  #pragma unroll
  for (int dt=0; dt<16; dt++){
    #pragma unroll
    for (int r=0;r<4;r++){
      pO[(qrow + lg*4 + r)*256 + dt*16 + lq] = f2bf(o[dt][r]);
    }
  }
}

// ---------------- combine (vectorized): plain sums + masked count + self + 1.5*q ----------------
// fine=1: loop c<129, valid = (c==128)||mask[c], self slot 129.
// fine=0: loop c<65,  valid = (c==64)||mask[2c]||mask[2c+1], self slot 65.
__global__ __launch_bounds__(256) void attn_reduce(
    const u16* __restrict__ pO, const float* __restrict__ pL,
    const int* __restrict__ mask, const u16* __restrict__ qb,
    u16* __restrict__ attn_out, int fine)
{
  __shared__ f32x4 redO[4][64];
  __shared__ float redL[4];
  __shared__ float scnt[2];
  int q = blockIdx.x, tid = threadIdx.x;
  int cg = tid >> 6, dq = tid & 63;
  int ncLoop = fine ? 129 : 65;
  int selfc  = fine ? 129 : 65;

  float mz = (tid < 128) ? ((mask[tid]==0) ? 1.f : 0.f) : 0.f;
  #pragma unroll
  for (int o=1;o<64;o<<=1) mz += __shfl_xor(mz, o);
  if ((tid&63)==0 && tid < 128) scnt[tid>>6] = mz;

  f32x4 acc = {0,0,0,0};
  float lsum = 0.f;
  for (int c = cg; c < ncLoop; c += 4){
    bool valid = fine ? (c==128 || mask[c]!=0)
                      : (c==64 || mask[2*c] || mask[2*c+1]);
    if (!valid) continue;
    u16x4 v = *(const u16x4*)(pO + ((size_t)c*512+q)*256 + dq*4);
    acc[0] += bf2f(v[0]); acc[1] += bf2f(v[1]);
    acc[2] += bf2f(v[2]); acc[3] += bf2f(v[3]);
    if (dq==0) lsum += pL[(size_t)c*512+q];
  }
  redO[cg][dq] = acc;
  if (dq==0) redL[cg] = lsum;
  __syncthreads();
  if (tid < 64){
    f32x4 s = redO[0][tid];
    f32x4 s1 = redO[1][tid], s2 = redO[2][tid], s3 = redO[3][tid];
    s[0]+=s1[0]+s2[0]+s3[0]; s[1]+=s1[1]+s2[1]+s3[1];
    s[2]+=s1[2]+s2[2]+s3[2]; s[3]+=s1[3]+s2[3]+s3[3];
    float den = redL[0]+redL[1]+redL[2]+redL[3] + 512.f*(scnt[0]+scnt[1]);
    float ls  = pL[(size_t)selfc*512 + q];
    u16x4 sv = *(const u16x4*)(pO + ((size_t)selfc*512+q)*256 + tid*4);
    u16x4 qv = *(const u16x4*)(qb + (size_t)q*256 + tid*4);
    u16x4 ov;
    #pragma unroll
    for (int j=0;j<4;j++)
      ov[j] = f2bf(s[j]/den + 0.5f*bf2f(sv[j])/ls + 1.5f*bf2f(qv[j]));
    *(u16x4*)(attn_out + (size_t)q*256 + tid*4) = ov;
  }
}

extern "C" void kernel_launch(void* const* d_in, const int* in_sizes, int n_in,
                              void* d_out, int out_size, void* d_ws, size_t ws_size,
                              hipStream_t stream)
{
  const float* x    = (const float*)d_in[0];
  const float* ck   = (const float*)d_in[1];
  const float* ln1g = (const float*)d_in[2];
  const float* ln1b = (const float*)d_in[3];
  const float* ln2g = (const float*)d_in[4];
  const float* ln2b = (const float*)d_in[5];
  const float* wk   = (const float*)d_in[6];
  const float* wc   = (const float*)d_in[7];
  const float* apw  = (const float*)d_in[8];
  const float* apb  = (const float*)d_in[9];
  const float* fcw  = (const float*)d_in[10];
  const float* fcb  = (const float*)d_in[11];
  const float* pjw  = (const float*)d_in[12];
  const float* pjb  = (const float*)d_in[13];
  const int*   mask = (const int*)d_in[14];
  float* out = (float*)d_out;

  char* wsb = (char*)d_ws;
  float* x1    = (float*)(wsb + 0);          // 512x512 f32
  float* x2    = (float*)(wsb + 1048576);    // 512x512 f32
  u16*   aoutb = (u16*)  (wsb + 2097152);    // 512x256 bf16
  u16*   x2nb  = (u16*)  (wsb + 2359296);    // 512x512 bf16
  u16*   xgT   = (u16*)  (wsb + 2883584);    // 256x1536 bf16
  u16*   apT   = (u16*)  (wsb + 3670016);    // 512x256 bf16
  u16*   fcT   = (u16*)  (wsb + 3932160);    // 2048x512 bf16
  u16*   pjT   = (u16*)  (wsb + 6029312);    // 512x2048 bf16
  u16*   qbf   = (u16*)  (wsb + 8126464);    // 512x256 bf16
  u16*   kbf   = (u16*)  (wsb + 8388608);    // 66048x256 bf16 -> ends 42205184
  float* pL    = (float*)(wsb + 42205184);   // up to 130x512 f32 (ends 42471424)
  // fine:   pO130 at 42471424 (34,078,720 B -> ends 76,550,144); needs ws >= 76550144
  // coarse: pO66  at 42340352 (r13 layout, ends 59,641,856); verified watermark 61.6MB
  const bool fine = (ws_size >= (size_t)76550144);
  u16*   pO    = (u16*)  (wsb + (fine ? 42471424 : 42340352));
  u16*   wkcb  = (u16*)  (wsb + 42471424);   // 3MB, pre-attn only (aliases pO region)
  u16*   hb    = (u16*)  (wsb + 42471424);   // 2MB, post-reduce only (aliases pO region)

  // prep (includes ln1) -> xgT -> conv gemm -> attn -> reduce -> tail
  prep_kernel<<<11648,256,0,stream>>>(x, ln1g, ln1b, wk, wc, apw, fcw, pjw, ck, mask,
      x1, wkcb, apT, fcT, pjT, kbf);
  xgT_kernel<<<256,256,0,stream>>>(x1, xgT);

  // conv GEMM (stacked, 8-wave K-split): q (rows<512) + k_cur (rows>=512)
  gemm4<0,false,true,8><<<dim3(8,32),512,0,stream>>>(wkcb, xgT, nullptr, nullptr,
      nullptr, qbf, kbf + (size_t)65536*256, 512, 1024, 256, 1536);

  // attention partials (XCD-swizzled 1-D grid)
  if (fine) attn_flash<1><<<2176,128,0,stream>>>(qbf, kbf, mask, pO, pL);
  else      attn_flash<0><<<1152,128,0,stream>>>(qbf, kbf, mask, pO, pL);
  attn_reduce<<<512,256,0,stream>>>(pO, pL, mask, qbf, aoutb, fine ? 1 : 0);

  // x2 = x1 + atten@ap_w + ap_b
  gemm4<0,true,false,4><<<dim3(16,16),256,0,stream>>>(aoutb, apT, apb, x1,
      x2, nullptr, nullptr, 512, 512, 512, 256);
  ln_kernel<true><<<512,256,0,stream>>>(x2, ln2g, ln2b, nullptr, x2nb);
  // h = swish(x2n@fc_w + fc_b)
  gemm4<1,false,true,4><<<dim3(64,16),256,0,stream>>>(x2nb, fcT, fcb, nullptr,
      nullptr, hb, hb, 4096, 512, 2048, 512);
  // out = x2 + h@proj_w + proj_b
  gemm4<0,true,false,8><<<dim3(16,16),512,0,stream>>>(hb, pjT, pjb, x2,
      out, nullptr, nullptr, 512, 512, 512, 2048);
}

// Round 18
// 113.738 us; speedup vs baseline: 1.0921x; 1.0921x over previous
//
#include <hip/hip_runtime.h>
#include <hip/hip_bf16.h>

typedef unsigned short u16;
typedef unsigned int u32;
typedef __attribute__((ext_vector_type(8))) short bf16x8;
typedef __attribute__((ext_vector_type(4))) short bf16x4;
typedef __attribute__((ext_vector_type(4))) float f32x4;
typedef __attribute__((ext_vector_type(8))) u16 u16x8;
typedef __attribute__((ext_vector_type(4))) u16 u16x4;
typedef __attribute__((ext_vector_type(4))) u32 u32x4;

__device__ __forceinline__ u16 f2bf(float x){
  __hip_bfloat16 h = __float2bfloat16(x);
  return __builtin_bit_cast(u16, h);
}
__device__ __forceinline__ float bf2f(u16 u){
  __hip_bfloat16 h = __builtin_bit_cast(__hip_bfloat16, u);
  return __bfloat162float(h);
}

// ---------------- LayerNorm over rows of 512 (used for ln2 only) ----------------
template<bool BF>
__global__ __launch_bounds__(256) void ln_kernel(const float* __restrict__ in,
    const float* __restrict__ g, const float* __restrict__ b,
    float* __restrict__ outf, u16* __restrict__ outb)
{
  int row = blockIdx.x, tid = threadIdx.x;
  const float* p = in + (size_t)row*512 + tid*2;
  float v0 = p[0], v1 = p[1];
  float s = v0+v1, ss = v0*v0+v1*v1;
  #pragma unroll
  for (int o=1;o<64;o<<=1){ s += __shfl_xor(s,o); ss += __shfl_xor(ss,o); }
  __shared__ float rs[4], rss[4];
  if ((tid&63)==0){ rs[tid>>6]=s; rss[tid>>6]=ss; }
  __syncthreads();
  s = rs[0]+rs[1]+rs[2]+rs[3]; ss = rss[0]+rss[1]+rss[2]+rss[3];
  float mean = s*(1.f/512.f);
  float var  = ss*(1.f/512.f) - mean*mean;
  float rstd = 1.f/sqrtf(var + 1e-5f);
  int d = tid*2;
  float o0 = (v0-mean)*rstd*g[d]   + b[d];
  float o1 = (v1-mean)*rstd*g[d+1] + b[d+1];
  if (BF){
    outb[(size_t)row*512+d]   = f2bf(o0);
    outb[(size_t)row*512+d+1] = f2bf(o1);
  } else {
    outf[(size_t)row*512+d]   = o0;
    outf[(size_t)row*512+d+1] = o1;
  }
}

// ---------------- conv input gather (transposed, bf16) ----------------
__global__ __launch_bounds__(256) void xgT_kernel(const float* __restrict__ x1, u16* __restrict__ xgT)
{
  int h = blockIdx.x, tid = threadIdx.x;
  #pragma unroll
  for (int rep=0;rep<6;rep++){
    int k = rep*256 + tid;
    int i = k/3, kk = k - i*3;
    int pos = 2*h - 1 + kk;
    float v = (pos >= 0 && pos < 512) ? x1[(size_t)i*512 + pos] : 0.f;
    xgT[(size_t)h*1536 + k] = f2bf(v);
  }
}

// ---------------- transpose+convert body (shared tile passed in) ----------------
__device__ __forceinline__ void transcvt_body(float (*t)[33],
    const float* __restrict__ in, u16* __restrict__ out, int K, int N, int bx, int by)
{
  int nb = bx*32, kb = by*32;
  int tx = threadIdx.x & 31, ty = threadIdx.x >> 5;
  #pragma unroll
  for (int i=0;i<32;i+=8) t[ty+i][tx] = in[(size_t)(kb+ty+i)*N + nb+tx];
  __syncthreads();
  #pragma unroll
  for (int i=0;i<32;i+=8) out[(size_t)(nb+ty+i)*K + kb+tx] = f2bf(t[tx][ty+i]);
}

// ---------------- fused prep: ln1 + cvt_cached + wk/wc cvt + 3 weight transposes ----------------
// partition: [0,512) ln1 | [512,8704) cached | [8704,9472) wkcb | [9472,9600) apT
//          | [9600,10624) fcT | [10624,11648) pjT
__global__ __launch_bounds__(256) void prep_kernel(
    const float* __restrict__ x, const float* __restrict__ ln1g, const float* __restrict__ ln1b,
    const float* __restrict__ wk, const float* __restrict__ wc,
    const float* __restrict__ apw, const float* __restrict__ fcw, const float* __restrict__ pjw,
    const float* __restrict__ ck, const int* __restrict__ mask,
    float* __restrict__ x1,
    u16* __restrict__ wkcb, u16* __restrict__ apT, u16* __restrict__ fcT,
    u16* __restrict__ pjT, u16* __restrict__ kbf)
{
  __shared__ float t[32][33];
  __shared__ float rs[4], rss[4];
  int b = blockIdx.x, tid = threadIdx.x;
  if (b < 512){                       // ln1: x -> x1 (f32)
    const float* p = x + (size_t)b*512 + tid*2;
    float v0 = p[0], v1 = p[1];
    float s = v0+v1, ss = v0*v0+v1*v1;
    #pragma unroll
    for (int o=1;o<64;o<<=1){ s += __shfl_xor(s,o); ss += __shfl_xor(ss,o); }
    if ((tid&63)==0){ rs[tid>>6]=s; rss[tid>>6]=ss; }
    __syncthreads();
    s = rs[0]+rs[1]+rs[2]+rs[3]; ss = rss[0]+rss[1]+rss[2]+rss[3];
    float mean = s*(1.f/512.f);
    float var  = ss*(1.f/512.f) - mean*mean;
    float rstd = 1.f/sqrtf(var + 1e-5f);
    int d = tid*2;
    x1[(size_t)b*512+d]   = (v0-mean)*rstd*ln1g[d]   + ln1b[d];
    x1[(size_t)b*512+d+1] = (v1-mean)*rstd*ln1g[d+1] + ln1b[d+1];
  } else if (b < 8704){               // cached_k -> bf16 (skip masked t blocks)
    int flat = (b-512)*256 + tid;
    int row = flat >> 5, seg = flat & 31;
    if (mask[row>>9] == 0) return;
    const float* src = ck + (size_t)row*256 + seg*8;
    u16x8 o;
    #pragma unroll
    for (int j=0;j<8;j++) o[j] = f2bf(src[j]);
    *(u16x8*)(kbf + (size_t)row*256 + seg*8) = o;
  } else if (b < 9472){               // wk|wc -> wkcb (stacked 1024x1536)
    size_t i = (size_t)((b-8704)*256 + tid)*8;
    const size_t half = (size_t)512*1536;
    const float* src = (i < half) ? (wk + i) : (wc + (i - half));
    u16x8 o;
    #pragma unroll
    for (int j=0;j<8;j++) o[j] = f2bf(src[j]);
    *(u16x8*)(wkcb + i) = o;
  } else if (b < 9600){               // apw f32[256][512] -> apT bf16[512][256]
    int f = b - 9472;
    transcvt_body(t, apw, apT, 256, 512, f & 15, f >> 4);
  } else if (b < 10624){              // fcw f32[512][2048] -> fcT bf16[2048][512]
    int f = b - 9600;
    transcvt_body(t, fcw, fcT, 512, 2048, f & 63, f >> 6);
  } else {                            // pjw f32[2048][512] -> pjT bf16[512][2048]
    int f = b - 10624;                // 1024 tiles: bx 0..15, by 0..63
    transcvt_body(t, pjw, pjT, 2048, 512, f & 15, f >> 4);
  }
}

// ---------------- bf16 MFMA GEMM, W-wave K-split: 32x32 tile ----------------
template<int ACT, bool WF32, bool WBF, int W>
__global__ __launch_bounds__(64*W) void gemm4(
    const u16* __restrict__ A, const u16* __restrict__ B,
    const float* __restrict__ bias, const float* __restrict__ resid,
    float* __restrict__ outF, u16* __restrict__ outB, u16* __restrict__ outB2,
    int rowSplit, int M, int N, int K)
{
  __shared__ float red[W][32][33];
  int tid = threadIdx.x;
  int w = tid >> 6, lane = tid & 63;
  int lq = lane & 15, lg = lane >> 4;
  int m0 = blockIdx.y*32, n0 = blockIdx.x*32;
  int Ks = K / W;
  int kbeg = w * Ks;
  f32x4 acc00={0,0,0,0}, acc01={0,0,0,0}, acc10={0,0,0,0}, acc11={0,0,0,0};
  const u16* pa0 = A + (size_t)(m0+lq)*K + kbeg + lg*8;
  const u16* pa1 = pa0 + (size_t)16*K;
  const u16* pb0 = B + (size_t)(n0+lq)*K + kbeg + lg*8;
  const u16* pb1 = pb0 + (size_t)16*K;
  #pragma unroll 2
  for (int k0=0;k0<Ks;k0+=32){
    bf16x8 a0 = *(const bf16x8*)(pa0+k0);
    bf16x8 a1 = *(const bf16x8*)(pa1+k0);
    bf16x8 b0 = *(const bf16x8*)(pb0+k0);
    bf16x8 b1 = *(const bf16x8*)(pb1+k0);
    acc00 = __builtin_amdgcn_mfma_f32_16x16x32_bf16(a0,b0,acc00,0,0,0);
    acc01 = __builtin_amdgcn_mfma_f32_16x16x32_bf16(a0,b1,acc01,0,0,0);
    acc10 = __builtin_amdgcn_mfma_f32_16x16x32_bf16(a1,b0,acc10,0,0,0);
    acc11 = __builtin_amdgcn_mfma_f32_16x16x32_bf16(a1,b1,acc11,0,0,0);
  }
  f32x4 accs[2][2] = {{acc00,acc01},{acc10,acc11}};
  #pragma unroll
  for (int mi=0;mi<2;mi++)
    #pragma unroll
    for (int ni=0;ni<2;ni++)
      #pragma unroll
      for (int r=0;r<4;r++)
        red[w][mi*16+lg*4+r][ni*16+lq] = accs[mi][ni][r];
  __syncthreads();
  #pragma unroll
  for (int rr=0;rr<16/W;rr++){
    int cell = rr*64*W + tid;        // 0..1023
    int row = cell >> 5, col = cell & 31;
    float v = 0.f;
    #pragma unroll
    for (int ww=0;ww<W;ww++) v += red[ww][row][col];
    int grow = m0 + row, gcol = n0 + col;
    if (bias)  v += bias[gcol];
    if (ACT==1) v = v/(1.f+__expf(-1.702f*v));
    if (resid) v += resid[(size_t)grow*N+gcol];
    if (WF32) outF[(size_t)grow*N+gcol] = v;
    if (WBF){
      if (grow < rowSplit) outB[(size_t)grow*N+gcol] = f2bf(v);
      else                 outB2[(size_t)(grow-rowSplit)*N+gcol] = f2bf(v);
    }
  }
}

// ---------------- flash attention (round-8/12/13 verified: 1024-key chunks, bf16 partials) ----------------
// grid (66, 16), 128 threads (2 waves, 16 q each): c<64 cached chunks (1024 keys),
// c=64 conv keys (512), c=65 self (keys=q).
// LDS per 32-key tile: elem(d,k) = (d>>4)*512 + k*16 + (d&15)  (16 KB, linear),
// staged via global_load_lds(16B) pre-swizzled source, double-buffered, counted vmcnt(8).
// PV k-perm + canonical tr_read + counted lgkm pipeline.
__global__ __launch_bounds__(128) void attn_flash(
    const u16* __restrict__ qb, const u16* __restrict__ keys,
    const int* __restrict__ mask,
    u16* __restrict__ pO, float* __restrict__ pL)
{
  __shared__ u16 kv[2][8192];
  int tid = threadIdx.x;
  int w = tid >> 6, lane = tid & 63, lq = lane & 15, lg = lane >> 4;
  int c = blockIdx.x, qt = blockIdx.y;
  const u16* kp = keys;
  int kstart = c * 1024, off = 0, nt = 32;
  if (c == 65) { kp = qb; kstart = 0; nt = 16; }
  else if (c == 64) { kstart = 65536; nt = 16; }
  else {
    int m0 = mask[2*c], m1 = mask[2*c+1];
    if (!m0 && !m1) return;
    off = m0 ? 0 : 512;
    nt = ((m0 && m1) ? 32 : 16);
  }
  int qbase = qt*32 + w*16;

  bf16x8 qf[8];
  {
    const u16* qrow = qb + (size_t)(qbase+lq)*256 + lg*8;
    #pragma unroll
    for (int s=0;s<8;s++) qf[s] = *(const bf16x8*)(qrow + s*32);
  }
  f32x4 o[16];
  #pragma unroll
  for (int i=0;i<16;i++) o[i] = (f32x4){0,0,0,0};
  float l_acc = 0.f;

  auto kv3 = (__attribute__((address_space(3))) char*)&kv[0][0];
  unsigned kvaddr0 = (unsigned)(unsigned long long)kv3;
  const char* gbase = (const char*)kp + (size_t)(kstart+off)*512;

  // 128 threads: 8 reps x 128 lanes x 16B = 16KB per tile
  #define STAGE(i, b) { \
    const char* tb = gbase + (size_t)(i)*16384; \
    _Pragma("unroll") \
    for (int rep=0; rep<8; rep++){ \
      int slot = rep*128 + tid; \
      int goff = ((slot&63)>>1)*512 + ((slot>>6)*16 + (slot&1)*8)*2; \
      __builtin_amdgcn_global_load_lds( \
        (const __attribute__((address_space(1))) unsigned*)(tb + goff), \
        (__attribute__((address_space(3))) unsigned*)(kv3 + (b)*16384 + (rep*128 + (tid & ~63))*16), \
        16, 0, 0); \
    } }

  #define ISSUE8(T, ab) \
    asm volatile( \
      "ds_read_b64_tr_b16 %0, %8 offset:0\n\t" \
      "ds_read_b64_tr_b16 %1, %8 offset:512\n\t" \
      "ds_read_b64_tr_b16 %2, %8 offset:1024\n\t" \
      "ds_read_b64_tr_b16 %3, %8 offset:1536\n\t" \
      "ds_read_b64_tr_b16 %4, %8 offset:2048\n\t" \
      "ds_read_b64_tr_b16 %5, %8 offset:2560\n\t" \
      "ds_read_b64_tr_b16 %6, %8 offset:3072\n\t" \
      "ds_read_b64_tr_b16 %7, %8 offset:3584\n\t" \
      : "=&v"(T[0]),"=&v"(T[1]),"=&v"(T[2]),"=&v"(T[3]), \
        "=&v"(T[4]),"=&v"(T[5]),"=&v"(T[6]),"=&v"(T[7]) \
      : "v"(ab) : "memory")

  #define MFMA4(T, base) { \
    bf16x8 v0_ = __builtin_shufflevector(T[0],T[1],0,1,2,3,4,5,6,7); \
    bf16x8 v1_ = __builtin_shufflevector(T[2],T[3],0,1,2,3,4,5,6,7); \
    bf16x8 v2_ = __builtin_shufflevector(T[4],T[5],0,1,2,3,4,5,6,7); \
    bf16x8 v3_ = __builtin_shufflevector(T[6],T[7],0,1,2,3,4,5,6,7); \
    o[(base)+0] = __builtin_amdgcn_mfma_f32_16x16x32_bf16(pa, v0_, o[(base)+0], 0,0,0); \
    o[(base)+1] = __builtin_amdgcn_mfma_f32_16x16x32_bf16(pa, v1_, o[(base)+1], 0,0,0); \
    o[(base)+2] = __builtin_amdgcn_mfma_f32_16x16x32_bf16(pa, v2_, o[(base)+2], 0,0,0); \
    o[(base)+3] = __builtin_amdgcn_mfma_f32_16x16x32_bf16(pa, v3_, o[(base)+3], 0,0,0); \
  }

  STAGE(0, 0);
  for (int i=0; i<nt; i++){
    int cur = i & 1;
    if (i+1 < nt){
      STAGE(i+1, cur^1);
      asm volatile("s_waitcnt vmcnt(8)" ::: "memory");
    } else {
      asm volatile("s_waitcnt vmcnt(0)" ::: "memory");
    }
    __syncthreads();

    // ---- QK^T (S^T = K * Q^T), A-frags as b128 from subtiled LDS ----
    const u16* kb = &kv[cur][0];
    f32x4 s0 = {0,0,0,0}, s1 = {0,0,0,0};
    #pragma unroll
    for (int s=0;s<8;s++){
      int e = (2*s + (lg>>1))*512 + lq*16 + (lg&1)*8;
      bf16x8 ka0 = *(const bf16x8*)(kb + e);
      bf16x8 ka1 = *(const bf16x8*)(kb + e + 256);
      s0 = __builtin_amdgcn_mfma_f32_16x16x32_bf16(ka0, qf[s], s0, 0,0,0);
      s1 = __builtin_amdgcn_mfma_f32_16x16x32_bf16(ka1, qf[s], s1, 0,0,0);
    }
    asm volatile("s_waitcnt lgkmcnt(0)" ::: "memory");

    // ---- PV tr_reads: issue two groups ahead, overlap exp/pack with latency ----
    unsigned trb = kvaddr0 + cur*16384 + lane*8;
    bf16x4 tA[8], tB[8], tC[8], tD[8];
    ISSUE8(tA, trb);
    ISSUE8(tB, trb + 4096);

    // ---- exp (no max); lane holds q=lq, keys {4lg+r} and {16+4lg+r} ----
    float p[8];
    #pragma unroll
    for (int r=0;r<4;r++){ p[r]   = __expf(s0[r]*0.0625f);
                           p[4+r] = __expf(s1[r]*0.0625f); }
    l_acc += (p[0]+p[1])+(p[2]+p[3])+((p[4]+p[5])+(p[6]+p[7]));
    // A-frag = own p values (k-perm: position j <-> key {4lg+j, 16+4lg+(j-4)})
    u32 w0 = (u32)f2bf(p[0]) | ((u32)f2bf(p[1])<<16);
    u32 w1 = (u32)f2bf(p[2]) | ((u32)f2bf(p[3])<<16);
    u32 w2 = (u32)f2bf(p[4]) | ((u32)f2bf(p[5])<<16);
    u32 w3 = (u32)f2bf(p[6]) | ((u32)f2bf(p[7])<<16);
    u32x4 fq = {w0,w1,w2,w3};
    bf16x8 pa = __builtin_bit_cast(bf16x8, fq);

    // ---- counted-wait pipeline ----
    asm volatile("s_waitcnt lgkmcnt(8)" ::: "memory");
    __builtin_amdgcn_sched_barrier(0);
    MFMA4(tA, 0);
    ISSUE8(tC, trb + 8192);
    asm volatile("s_waitcnt lgkmcnt(8)" ::: "memory");
    __builtin_amdgcn_sched_barrier(0);
    MFMA4(tB, 4);
    ISSUE8(tD, trb + 12288);
    asm volatile("s_waitcnt lgkmcnt(8)" ::: "memory");
    __builtin_amdgcn_sched_barrier(0);
    MFMA4(tC, 8);
    asm volatile("s_waitcnt lgkmcnt(0)" ::: "memory");
    __builtin_amdgcn_sched_barrier(0);
    MFMA4(tD, 12);
    __syncthreads();
  }
  #undef STAGE
  #undef ISSUE8
  #undef MFMA4

  l_acc += __shfl_xor(l_acc, 16);
  l_acc += __shfl_xor(l_acc, 32);
  size_t qrow = (size_t)c*512 + qbase;
  if (lane < 16) pL[qrow + lq] = l_acc;
  // o[dt][r] = O[q = 4lg+r][d = dt*16+lq]
  #pragma unroll
  for (int dt=0; dt<16; dt++){
    #pragma unroll
    for (int r=0;r<4;r++){
      pO[(qrow + lg*4 + r)*256 + dt*16 + lq] = f2bf(o[dt][r]);
    }
  }
}

// ---------------- combine (vectorized): plain sums + masked count + self + 1.5*q ----------------
// block = one q row, 256 threads = 4 chunk-groups x 64 d-quads; u16x4 coalesced loads.
__global__ __launch_bounds__(256) void attn_reduce(
    const u16* __restrict__ pO, const float* __restrict__ pL,
    const int* __restrict__ mask, const u16* __restrict__ qb,
    u16* __restrict__ attn_out)
{
  __shared__ f32x4 redO[4][64];
  __shared__ float redL[4];
  __shared__ float scnt[2];
  int q = blockIdx.x, tid = threadIdx.x;
  int cg = tid >> 6, dq = tid & 63;

  // masked-t count (wave-parallel)
  float mz = (tid < 128) ? ((mask[tid]==0) ? 1.f : 0.f) : 0.f;
  #pragma unroll
  for (int o=1;o<64;o<<=1) mz += __shfl_xor(mz, o);
  if ((tid&63)==0 && tid < 128) scnt[tid>>6] = mz;

  f32x4 acc = {0,0,0,0};
  float lsum = 0.f;
  for (int c = cg; c < 65; c += 4){
    bool valid = (c==64) || mask[2*c] || mask[2*c+1];
    if (!valid) continue;
    u16x4 v = *(const u16x4*)(pO + ((size_t)c*512+q)*256 + dq*4);
    acc[0] += bf2f(v[0]); acc[1] += bf2f(v[1]);
    acc[2] += bf2f(v[2]); acc[3] += bf2f(v[3]);
    if (dq==0) lsum += pL[(size_t)c*512+q];
  }
  redO[cg][dq] = acc;
  if (dq==0) redL[cg] = lsum;
  __syncthreads();
  if (tid < 64){
    f32x4 s = redO[0][tid];
    f32x4 s1 = redO[1][tid], s2 = redO[2][tid], s3 = redO[3][tid];
    s[0]+=s1[0]+s2[0]+s3[0]; s[1]+=s1[1]+s2[1]+s3[1];
    s[2]+=s1[2]+s2[2]+s3[2]; s[3]+=s1[3]+s2[3]+s3[3];
    float den = redL[0]+redL[1]+redL[2]+redL[3] + 512.f*(scnt[0]+scnt[1]);
    float ls  = pL[(size_t)65*512 + q];
    u16x4 sv = *(const u16x4*)(pO + ((size_t)65*512+q)*256 + tid*4);
    u16x4 qv = *(const u16x4*)(qb + (size_t)q*256 + tid*4);
    u16x4 ov;
    #pragma unroll
    for (int j=0;j<4;j++)
      ov[j] = f2bf(s[j]/den + 0.5f*bf2f(sv[j])/ls + 1.5f*bf2f(qv[j]));
    *(u16x4*)(attn_out + (size_t)q*256 + tid*4) = ov;
  }
}

extern "C" void kernel_launch(void* const* d_in, const int* in_sizes, int n_in,
                              void* d_out, int out_size, void* d_ws, size_t ws_size,
                              hipStream_t stream)
{
  const float* x    = (const float*)d_in[0];
  const float* ck   = (const float*)d_in[1];
  const float* ln1g = (const float*)d_in[2];
  const float* ln1b = (const float*)d_in[3];
  const float* ln2g = (const float*)d_in[4];
  const float* ln2b = (const float*)d_in[5];
  const float* wk   = (const float*)d_in[6];
  const float* wc   = (const float*)d_in[7];
  const float* apw  = (const float*)d_in[8];
  const float* apb  = (const float*)d_in[9];
  const float* fcw  = (const float*)d_in[10];
  const float* fcb  = (const float*)d_in[11];
  const float* pjw  = (const float*)d_in[12];
  const float* pjb  = (const float*)d_in[13];
  const int*   mask = (const int*)d_in[14];
  float* out = (float*)d_out;

  char* wsb = (char*)d_ws;
  float* x1    = (float*)(wsb + 0);          // 512x512 f32
  float* x2    = (float*)(wsb + 1048576);    // 512x512 f32
  u16*   aoutb = (u16*)  (wsb + 2097152);    // 512x256 bf16
  u16*   x2nb  = (u16*)  (wsb + 2359296);    // 512x512 bf16
  u16*   xgT   = (u16*)  (wsb + 2883584);    // 256x1536 bf16
  u16*   apT   = (u16*)  (wsb + 3670016);    // 512x256 bf16
  u16*   fcT   = (u16*)  (wsb + 3932160);    // 2048x512 bf16
  u16*   pjT   = (u16*)  (wsb + 6029312);    // 512x2048 bf16
  u16*   qbf   = (u16*)  (wsb + 8126464);    // 512x256 bf16
  u16*   kbf   = (u16*)  (wsb + 8388608);    // 66048x256 bf16 -> ends 42205184
  float* pL    = (float*)(wsb + 42205184);   // 66x512 f32
  u16*   pO    = (u16*)  (wsb + 42340352);   // 66x512x256 bf16 (ends 59641856)
  u16*   wkcb  = (u16*)  (wsb + 42340352);   // 1024x1536 bf16, aliases pO (conv runs before attn)
  u16*   hb    = (u16*)  (wsb + 42340352);   // 512x2048 bf16, aliases pO (used after reduce)

  // prep (includes ln1) -> xgT -> conv gemm -> attn -> reduce -> tail
  prep_kernel<<<11648,256,0,stream>>>(x, ln1g, ln1b, wk, wc, apw, fcw, pjw, ck, mask,
      x1, wkcb, apT, fcT, pjT, kbf);
  xgT_kernel<<<256,256,0,stream>>>(x1, xgT);

  // conv GEMM (stacked, 8-wave K-split): q (rows<512) + k_cur (rows>=512)
  gemm4<0,false,true,8><<<dim3(8,32),512,0,stream>>>(wkcb, xgT, nullptr, nullptr,
      nullptr, qbf, kbf + (size_t)65536*256, 512, 1024, 256, 1536);

  // attention partials: 64 cached chunks + conv chunk (c=64) + self chunk (c=65)
  attn_flash<<<dim3(66,16),128,0,stream>>>(qbf, kbf, mask, pO, pL);
  attn_reduce<<<512,256,0,stream>>>(pO, pL, mask, qbf, aoutb);

  // x2 = x1 + atten@ap_w + ap_b
  gemm4<0,true,false,4><<<dim3(16,16),256,0,stream>>>(aoutb, apT, apb, x1,
      x2, nullptr, nullptr, 512, 512, 512, 256);
  ln_kernel<true><<<512,256,0,stream>>>(x2, ln2g, ln2b, nullptr, x2nb);
  // h = swish(x2n@fc_w + fc_b)
  gemm4<1,false,true,4><<<dim3(64,16),256,0,stream>>>(x2nb, fcT, fcb, nullptr,
      nullptr, hb, hb, 4096, 512, 2048, 512);
  // out = x2 + h@proj_w + proj_b
  gemm4<0,true,false,8><<<dim3(16,16),512,0,stream>>>(hb, pjT, pjb, x2,
      out, nullptr, nullptr, 512, 512, 512, 2048);
}

// Round 19
// 112.894 us; speedup vs baseline: 1.1002x; 1.0075x over previous
//
#include <hip/hip_runtime.h>
#include <hip/hip_bf16.h>

typedef unsigned short u16;
typedef unsigned int u32;
typedef __attribute__((ext_vector_type(8))) short bf16x8;
typedef __attribute__((ext_vector_type(4))) short bf16x4;
typedef __attribute__((ext_vector_type(4))) float f32x4;
typedef __attribute__((ext_vector_type(8))) u16 u16x8;
typedef __attribute__((ext_vector_type(4))) u16 u16x4;
typedef __attribute__((ext_vector_type(4))) u32 u32x4;

__device__ __forceinline__ u16 f2bf(float x){
  __hip_bfloat16 h = __float2bfloat16(x);
  return __builtin_bit_cast(u16, h);
}
__device__ __forceinline__ float bf2f(u16 u){
  __hip_bfloat16 h = __builtin_bit_cast(__hip_bfloat16, u);
  return __bfloat162float(h);
}

// ---------------- LayerNorm over rows of 512 (used for ln2 only) ----------------
template<bool BF>
__global__ __launch_bounds__(256) void ln_kernel(const float* __restrict__ in,
    const float* __restrict__ g, const float* __restrict__ b,
    float* __restrict__ outf, u16* __restrict__ outb)
{
  int row = blockIdx.x, tid = threadIdx.x;
  const float* p = in + (size_t)row*512 + tid*2;
  float v0 = p[0], v1 = p[1];
  float s = v0+v1, ss = v0*v0+v1*v1;
  #pragma unroll
  for (int o=1;o<64;o<<=1){ s += __shfl_xor(s,o); ss += __shfl_xor(ss,o); }
  __shared__ float rs[4], rss[4];
  if ((tid&63)==0){ rs[tid>>6]=s; rss[tid>>6]=ss; }
  __syncthreads();
  s = rs[0]+rs[1]+rs[2]+rs[3]; ss = rss[0]+rss[1]+rss[2]+rss[3];
  float mean = s*(1.f/512.f);
  float var  = ss*(1.f/512.f) - mean*mean;
  float rstd = 1.f/sqrtf(var + 1e-5f);
  int d = tid*2;
  float o0 = (v0-mean)*rstd*g[d]   + b[d];
  float o1 = (v1-mean)*rstd*g[d+1] + b[d+1];
  if (BF){
    outb[(size_t)row*512+d]   = f2bf(o0);
    outb[(size_t)row*512+d+1] = f2bf(o1);
  } else {
    outf[(size_t)row*512+d]   = o0;
    outf[(size_t)row*512+d+1] = o1;
  }
}

// ---------------- conv input gather (transposed, bf16) ----------------
__global__ __launch_bounds__(256) void xgT_kernel(const float* __restrict__ x1, u16* __restrict__ xgT)
{
  int h = blockIdx.x, tid = threadIdx.x;
  #pragma unroll
  for (int rep=0;rep<6;rep++){
    int k = rep*256 + tid;
    int i = k/3, kk = k - i*3;
    int pos = 2*h - 1 + kk;
    float v = (pos >= 0 && pos < 512) ? x1[(size_t)i*512 + pos] : 0.f;
    xgT[(size_t)h*1536 + k] = f2bf(v);
  }
}

// ---------------- transpose+convert body, 128-thread variant ----------------
__device__ __forceinline__ void transcvt128(float (*t)[33],
    const float* __restrict__ in, u16* __restrict__ out, int K, int N, int bx, int by)
{
  int nb = bx*32, kb = by*32;
  int tx = threadIdx.x & 31, ty = threadIdx.x >> 5;   // ty 0..3
  #pragma unroll
  for (int i=0;i<32;i+=4) t[ty+i][tx] = in[(size_t)(kb+ty+i)*N + nb+tx];
  __syncthreads();
  #pragma unroll
  for (int i=0;i<32;i+=4) out[(size_t)(nb+ty+i)*K + kb+tx] = f2bf(t[tx][ty+i]);
}

// ---------------- fused prep: ln1 + cvt_cached + wk/wc cvt ----------------
// partition: [0,512) ln1 | [512,8704) cached | [8704,9472) wkcb
__global__ __launch_bounds__(256) void prep_kernel(
    const float* __restrict__ x, const float* __restrict__ ln1g, const float* __restrict__ ln1b,
    const float* __restrict__ wk, const float* __restrict__ wc,
    const float* __restrict__ ck, const int* __restrict__ mask,
    float* __restrict__ x1, u16* __restrict__ wkcb, u16* __restrict__ kbf)
{
  __shared__ float rs[4], rss[4];
  int b = blockIdx.x, tid = threadIdx.x;
  if (b < 512){                       // ln1: x -> x1 (f32)
    const float* p = x + (size_t)b*512 + tid*2;
    float v0 = p[0], v1 = p[1];
    float s = v0+v1, ss = v0*v0+v1*v1;
    #pragma unroll
    for (int o=1;o<64;o<<=1){ s += __shfl_xor(s,o); ss += __shfl_xor(ss,o); }
    if ((tid&63)==0){ rs[tid>>6]=s; rss[tid>>6]=ss; }
    __syncthreads();
    s = rs[0]+rs[1]+rs[2]+rs[3]; ss = rss[0]+rss[1]+rss[2]+rss[3];
    float mean = s*(1.f/512.f);
    float var  = ss*(1.f/512.f) - mean*mean;
    float rstd = 1.f/sqrtf(var + 1e-5f);
    int d = tid*2;
    x1[(size_t)b*512+d]   = (v0-mean)*rstd*ln1g[d]   + ln1b[d];
    x1[(size_t)b*512+d+1] = (v1-mean)*rstd*ln1g[d+1] + ln1b[d+1];
  } else if (b < 8704){               // cached_k -> bf16 (skip masked t blocks)
    int flat = (b-512)*256 + tid;
    int row = flat >> 5, seg = flat & 31;
    if (mask[row>>9] == 0) return;
    const float* src = ck + (size_t)row*256 + seg*8;
    u16x8 o;
    #pragma unroll
    for (int j=0;j<8;j++) o[j] = f2bf(src[j]);
    *(u16x8*)(kbf + (size_t)row*256 + seg*8) = o;
  } else {                            // wk|wc -> wkcb (stacked 1024x1536)
    size_t i = (size_t)((b-8704)*256 + tid)*8;
    const size_t half = (size_t)512*1536;
    const float* src = (i < half) ? (wk + i) : (wc + (i - half));
    u16x8 o;
    #pragma unroll
    for (int j=0;j<8;j++) o[j] = f2bf(src[j]);
    *(u16x8*)(wkcb + i) = o;
  }
}

// ---------------- bf16 MFMA GEMM, W-wave K-split: 32x32 tile ----------------
template<int ACT, bool WF32, bool WBF, int W>
__global__ __launch_bounds__(64*W) void gemm4(
    const u16* __restrict__ A, const u16* __restrict__ B,
    const float* __restrict__ bias, const float* __restrict__ resid,
    float* __restrict__ outF, u16* __restrict__ outB, u16* __restrict__ outB2,
    int rowSplit, int M, int N, int K)
{
  __shared__ float red[W][32][33];
  int tid = threadIdx.x;
  int w = tid >> 6, lane = tid & 63;
  int lq = lane & 15, lg = lane >> 4;
  int m0 = blockIdx.y*32, n0 = blockIdx.x*32;
  int Ks = K / W;
  int kbeg = w * Ks;
  f32x4 acc00={0,0,0,0}, acc01={0,0,0,0}, acc10={0,0,0,0}, acc11={0,0,0,0};
  const u16* pa0 = A + (size_t)(m0+lq)*K + kbeg + lg*8;
  const u16* pa1 = pa0 + (size_t)16*K;
  const u16* pb0 = B + (size_t)(n0+lq)*K + kbeg + lg*8;
  const u16* pb1 = pb0 + (size_t)16*K;
  #pragma unroll 2
  for (int k0=0;k0<Ks;k0+=32){
    bf16x8 a0 = *(const bf16x8*)(pa0+k0);
    bf16x8 a1 = *(const bf16x8*)(pa1+k0);
    bf16x8 b0 = *(const bf16x8*)(pb0+k0);
    bf16x8 b1 = *(const bf16x8*)(pb1+k0);
    acc00 = __builtin_amdgcn_mfma_f32_16x16x32_bf16(a0,b0,acc00,0,0,0);
    acc01 = __builtin_amdgcn_mfma_f32_16x16x32_bf16(a0,b1,acc01,0,0,0);
    acc10 = __builtin_amdgcn_mfma_f32_16x16x32_bf16(a1,b0,acc10,0,0,0);
    acc11 = __builtin_amdgcn_mfma_f32_16x16x32_bf16(a1,b1,acc11,0,0,0);
  }
  f32x4 accs[2][2] = {{acc00,acc01},{acc10,acc11}};
  #pragma unroll
  for (int mi=0;mi<2;mi++)
    #pragma unroll
    for (int ni=0;ni<2;ni++)
      #pragma unroll
      for (int r=0;r<4;r++)
        red[w][mi*16+lg*4+r][ni*16+lq] = accs[mi][ni][r];
  __syncthreads();
  #pragma unroll
  for (int rr=0;rr<16/W;rr++){
    int cell = rr*64*W + tid;        // 0..1023
    int row = cell >> 5, col = cell & 31;
    float v = 0.f;
    #pragma unroll
    for (int ww=0;ww<W;ww++) v += red[ww][row][col];
    int grow = m0 + row, gcol = n0 + col;
    if (bias)  v += bias[gcol];
    if (ACT==1) v = v/(1.f+__expf(-1.702f*v));
    if (resid) v += resid[(size_t)grow*N+gcol];
    if (WF32) outF[(size_t)grow*N+gcol] = v;
    if (WBF){
      if (grow < rowSplit) outB[(size_t)grow*N+gcol] = f2bf(v);
      else                 outB2[(size_t)(grow-rowSplit)*N+gcol] = f2bf(v);
    }
  }
}

// ---------------- flash attention (r13-verified core) + shadow weight transposes ----------------
// 1-D grid 3232: blocks [0,1056) = attention (c = bid%66, qt = bid/66 — r13 mapping);
// blocks [1056,3232) = apT/fcT/pjT transposes (no attention dependency; run in the
// occupancy shadow of the latency-bound attention blocks; LDS tile overlays kv buffer).
// Attention: c<64 cached chunks (1024 keys, mask-gated), c=64 conv keys, c=65 self.
// LDS per 32-key tile: elem(d,k) = (d>>4)*512 + k*16 + (d&15) (16 KB), double-buffered,
// global_load_lds(16B) pre-swizzled source, counted vmcnt(8); PV k-perm + canonical
// tr_read + counted lgkm pipeline.
__global__ __launch_bounds__(128) void attn_flash(
    const u16* __restrict__ qb, const u16* __restrict__ keys,
    const int* __restrict__ mask,
    const float* __restrict__ apw, const float* __restrict__ fcw, const float* __restrict__ pjw,
    u16* __restrict__ apT, u16* __restrict__ fcT, u16* __restrict__ pjT,
    u16* __restrict__ pO, float* __restrict__ pL)
{
  __shared__ u16 kv[2][8192];
  int tid = threadIdx.x;
  int bid = blockIdx.x;
  if (bid >= 1056){                   // ---- shadow transposes ----
    int f = bid - 1056;
    float (*t)[33] = reinterpret_cast<float(*)[33]>(&kv[0][0]);
    if (f < 128)       transcvt128(t, apw, apT, 256, 512, f & 15, f >> 4);
    else if (f < 1152) transcvt128(t, fcw, fcT, 512, 2048, (f-128) & 63, (f-128) >> 6);
    else               transcvt128(t, pjw, pjT, 2048, 512, (f-1152) & 15, (f-1152) >> 4);
    return;
  }
  int w = tid >> 6, lane = tid & 63, lq = lane & 15, lg = lane >> 4;
  int c = bid % 66, qt = bid / 66;
  const u16* kp = keys;
  int kstart = c * 1024, off = 0, nt = 32;
  if (c == 65) { kp = qb; kstart = 0; nt = 16; }
  else if (c == 64) { kstart = 65536; nt = 16; }
  else {
    int m0 = mask[2*c], m1 = mask[2*c+1];
    if (!m0 && !m1) return;
    off = m0 ? 0 : 512;
    nt = ((m0 && m1) ? 32 : 16);
  }
  int qbase = qt*32 + w*16;

  bf16x8 qf[8];
  {
    const u16* qrow = qb + (size_t)(qbase+lq)*256 + lg*8;
    #pragma unroll
    for (int s=0;s<8;s++) qf[s] = *(const bf16x8*)(qrow + s*32);
  }
  f32x4 o[16];
  #pragma unroll
  for (int i=0;i<16;i++) o[i] = (f32x4){0,0,0,0};
  float l_acc = 0.f;

  auto kv3 = (__attribute__((address_space(3))) char*)&kv[0][0];
  unsigned kvaddr0 = (unsigned)(unsigned long long)kv3;
  const char* gbase = (const char*)kp + (size_t)(kstart+off)*512;

  // 128 threads: 8 reps x 128 lanes x 16B = 16KB per tile
  #define STAGE(i, b) { \
    const char* tb = gbase + (size_t)(i)*16384; \
    _Pragma("unroll") \
    for (int rep=0; rep<8; rep++){ \
      int slot = rep*128 + tid; \
      int goff = ((slot&63)>>1)*512 + ((slot>>6)*16 + (slot&1)*8)*2; \
      __builtin_amdgcn_global_load_lds( \
        (const __attribute__((address_space(1))) unsigned*)(tb + goff), \
        (__attribute__((address_space(3))) unsigned*)(kv3 + (b)*16384 + (rep*128 + (tid & ~63))*16), \
        16, 0, 0); \
    } }

  #define ISSUE8(T, ab) \
    asm volatile( \
      "ds_read_b64_tr_b16 %0, %8 offset:0\n\t" \
      "ds_read_b64_tr_b16 %1, %8 offset:512\n\t" \
      "ds_read_b64_tr_b16 %2, %8 offset:1024\n\t" \
      "ds_read_b64_tr_b16 %3, %8 offset:1536\n\t" \
      "ds_read_b64_tr_b16 %4, %8 offset:2048\n\t" \
      "ds_read_b64_tr_b16 %5, %8 offset:2560\n\t" \
      "ds_read_b64_tr_b16 %6, %8 offset:3072\n\t" \
      "ds_read_b64_tr_b16 %7, %8 offset:3584\n\t" \
      : "=&v"(T[0]),"=&v"(T[1]),"=&v"(T[2]),"=&v"(T[3]), \
        "=&v"(T[4]),"=&v"(T[5]),"=&v"(T[6]),"=&v"(T[7]) \
      : "v"(ab) : "memory")

  #define MFMA4(T, base) { \
    bf16x8 v0_ = __builtin_shufflevector(T[0],T[1],0,1,2,3,4,5,6,7); \
    bf16x8 v1_ = __builtin_shufflevector(T[2],T[3],0,1,2,3,4,5,6,7); \
    bf16x8 v2_ = __builtin_shufflevector(T[4],T[5],0,1,2,3,4,5,6,7); \
    bf16x8 v3_ = __builtin_shufflevector(T[6],T[7],0,1,2,3,4,5,6,7); \
    o[(base)+0] = __builtin_amdgcn_mfma_f32_16x16x32_bf16(pa, v0_, o[(base)+0], 0,0,0); \
    o[(base)+1] = __builtin_amdgcn_mfma_f32_16x16x32_bf16(pa, v1_, o[(base)+1], 0,0,0); \
    o[(base)+2] = __builtin_amdgcn_mfma_f32_16x16x32_bf16(pa, v2_, o[(base)+2], 0,0,0); \
    o[(base)+3] = __builtin_amdgcn_mfma_f32_16x16x32_bf16(pa, v3_, o[(base)+3], 0,0,0); \
  }

  STAGE(0, 0);
  for (int i=0; i<nt; i++){
    int cur = i & 1;
    if (i+1 < nt){
      STAGE(i+1, cur^1);
      asm volatile("s_waitcnt vmcnt(8)" ::: "memory");
    } else {
      asm volatile("s_waitcnt vmcnt(0)" ::: "memory");
    }
    __syncthreads();

    // ---- QK^T (S^T = K * Q^T), A-frags as b128 from subtiled LDS ----
    const u16* kb = &kv[cur][0];
    f32x4 s0 = {0,0,0,0}, s1 = {0,0,0,0};
    #pragma unroll
    for (int s=0;s<8;s++){
      int e = (2*s + (lg>>1))*512 + lq*16 + (lg&1)*8;
      bf16x8 ka0 = *(const bf16x8*)(kb + e);
      bf16x8 ka1 = *(const bf16x8*)(kb + e + 256);
      s0 = __builtin_amdgcn_mfma_f32_16x16x32_bf16(ka0, qf[s], s0, 0,0,0);
      s1 = __builtin_amdgcn_mfma_f32_16x16x32_bf16(ka1, qf[s], s1, 0,0,0);
    }
    asm volatile("s_waitcnt lgkmcnt(0)" ::: "memory");

    // ---- PV tr_reads: issue two groups ahead, overlap exp/pack with latency ----
    unsigned trb = kvaddr0 + cur*16384 + lane*8;
    bf16x4 tA[8], tB[8], tC[8], tD[8];
    ISSUE8(tA, trb);
    ISSUE8(tB, trb + 4096);

    // ---- exp (no max); lane holds q=lq, keys {4lg+r} and {16+4lg+r} ----
    float p[8];
    #pragma unroll
    for (int r=0;r<4;r++){ p[r]   = __expf(s0[r]*0.0625f);
                           p[4+r] = __expf(s1[r]*0.0625f); }
    l_acc += (p[0]+p[1])+(p[2]+p[3])+((p[4]+p[5])+(p[6]+p[7]));
    // A-frag = own p values (k-perm: position j <-> key {4lg+j, 16+4lg+(j-4)})
    u32 w0 = (u32)f2bf(p[0]) | ((u32)f2bf(p[1])<<16);
    u32 w1 = (u32)f2bf(p[2]) | ((u32)f2bf(p[3])<<16);
    u32 w2 = (u32)f2bf(p[4]) | ((u32)f2bf(p[5])<<16);
    u32 w3 = (u32)f2bf(p[6]) | ((u32)f2bf(p[7])<<16);
    u32x4 fq = {w0,w1,w2,w3};
    bf16x8 pa = __builtin_bit_cast(bf16x8, fq);

    // ---- counted-wait pipeline ----
    asm volatile("s_waitcnt lgkmcnt(8)" ::: "memory");
    __builtin_amdgcn_sched_barrier(0);
    MFMA4(tA, 0);
    ISSUE8(tC, trb + 8192);
    asm volatile("s_waitcnt lgkmcnt(8)" ::: "memory");
    __builtin_amdgcn_sched_barrier(0);
    MFMA4(tB, 4);
    ISSUE8(tD, trb + 12288);
    asm volatile("s_waitcnt lgkmcnt(8)" ::: "memory");
    __builtin_amdgcn_sched_barrier(0);
    MFMA4(tC, 8);
    asm volatile("s_waitcnt lgkmcnt(0)" ::: "memory");
    __builtin_amdgcn_sched_barrier(0);
    MFMA4(tD, 12);
    __syncthreads();
  }
  #undef STAGE
  #undef ISSUE8
  #undef MFMA4

  l_acc += __shfl_xor(l_acc, 16);
  l_acc += __shfl_xor(l_acc, 32);
  size_t qrow = (size_t)c*512 + qbase;
  if (lane < 16) pL[qrow + lq] = l_acc;
  // o[dt][r] = O[q = 4lg+r][d = dt*16+lq]
  #pragma unroll
  for (int dt=0; dt<16; dt++){
    #pragma unroll
    for (int r=0;r<4;r++){
      pO[(qrow + lg*4 + r)*256 + dt*16 + lq] = f2bf(o[dt][r]);
    }
  }
}

// ---------------- combine (vectorized): plain sums + masked count + self + 1.5*q ----------------
__global__ __launch_bounds__(256) void attn_reduce(
    const u16* __restrict__ pO, const float* __restrict__ pL,
    const int* __restrict__ mask, const u16* __restrict__ qb,
    u16* __restrict__ attn_out)
{
  __shared__ f32x4 redO[4][64];
  __shared__ float redL[4];
  __shared__ float scnt[2];
  int q = blockIdx.x, tid = threadIdx.x;
  int cg = tid >> 6, dq = tid & 63;

  float mz = (tid < 128) ? ((mask[tid]==0) ? 1.f : 0.f) : 0.f;
  #pragma unroll
  for (int o=1;o<64;o<<=1) mz += __shfl_xor(mz, o);
  if ((tid&63)==0 && tid < 128) scnt[tid>>6] = mz;

  f32x4 acc = {0,0,0,0};
  float lsum = 0.f;
  for (int c = cg; c < 65; c += 4){
    bool valid = (c==64) || mask[2*c] || mask[2*c+1];
    if (!valid) continue;
    u16x4 v = *(const u16x4*)(pO + ((size_t)c*512+q)*256 + dq*4);
    acc[0] += bf2f(v[0]); acc[1] += bf2f(v[1]);
    acc[2] += bf2f(v[2]); acc[3] += bf2f(v[3]);
    if (dq==0) lsum += pL[(size_t)c*512+q];
  }
  redO[cg][dq] = acc;
  if (dq==0) redL[cg] = lsum;
  __syncthreads();
  if (tid < 64){
    f32x4 s = redO[0][tid];
    f32x4 s1 = redO[1][tid], s2 = redO[2][tid], s3 = redO[3][tid];
    s[0]+=s1[0]+s2[0]+s3[0]; s[1]+=s1[1]+s2[1]+s3[1];
    s[2]+=s1[2]+s2[2]+s3[2]; s[3]+=s1[3]+s2[3]+s3[3];
    float den = redL[0]+redL[1]+redL[2]+redL[3] + 512.f*(scnt[0]+scnt[1]);
    float ls  = pL[(size_t)65*512 + q];
    u16x4 sv = *(const u16x4*)(pO + ((size_t)65*512+q)*256 + tid*4);
    u16x4 qv = *(const u16x4*)(qb + (size_t)q*256 + tid*4);
    u16x4 ov;
    #pragma unroll
    for (int j=0;j<4;j++)
      ov[j] = f2bf(s[j]/den + 0.5f*bf2f(sv[j])/ls + 1.5f*bf2f(qv[j]));
    *(u16x4*)(attn_out + (size_t)q*256 + tid*4) = ov;
  }
}

extern "C" void kernel_launch(void* const* d_in, const int* in_sizes, int n_in,
                              void* d_out, int out_size, void* d_ws, size_t ws_size,
                              hipStream_t stream)
{
  const float* x    = (const float*)d_in[0];
  const float* ck   = (const float*)d_in[1];
  const float* ln1g = (const float*)d_in[2];
  const float* ln1b = (const float*)d_in[3];
  const float* ln2g = (const float*)d_in[4];
  const float* ln2b = (const float*)d_in[5];
  const float* wk   = (const float*)d_in[6];
  const float* wc   = (const float*)d_in[7];
  const float* apw  = (const float*)d_in[8];
  const float* apb  = (const float*)d_in[9];
  const float* fcw  = (const float*)d_in[10];
  const float* fcb  = (const float*)d_in[11];
  const float* pjw  = (const float*)d_in[12];
  const float* pjb  = (const float*)d_in[13];
  const int*   mask = (const int*)d_in[14];
  float* out = (float*)d_out;

  char* wsb = (char*)d_ws;
  float* x1    = (float*)(wsb + 0);          // 512x512 f32
  float* x2    = (float*)(wsb + 1048576);    // 512x512 f32
  u16*   aoutb = (u16*)  (wsb + 2097152);    // 512x256 bf16
  u16*   x2nb  = (u16*)  (wsb + 2359296);    // 512x512 bf16
  u16*   xgT   = (u16*)  (wsb + 2883584);    // 256x1536 bf16
  u16*   apT   = (u16*)  (wsb + 3670016);    // 512x256 bf16
  u16*   fcT   = (u16*)  (wsb + 3932160);    // 2048x512 bf16
  u16*   pjT   = (u16*)  (wsb + 6029312);    // 512x2048 bf16
  u16*   qbf   = (u16*)  (wsb + 8126464);    // 512x256 bf16
  u16*   kbf   = (u16*)  (wsb + 8388608);    // 66048x256 bf16 -> ends 42205184
  float* pL    = (float*)(wsb + 42205184);   // 66x512 f32
  u16*   pO    = (u16*)  (wsb + 42340352);   // 66x512x256 bf16 (ends 59641856)
  u16*   wkcb  = (u16*)  (wsb + 42340352);   // 1024x1536 bf16, aliases pO (conv runs before attn)
  u16*   hb    = (u16*)  (wsb + 42340352);   // 512x2048 bf16, aliases pO (used after reduce)

  // prep (ln1 + cached cvt + conv weights) -> xgT -> conv gemm -> attn(+shadow transposes) -> reduce -> tail
  prep_kernel<<<9472,256,0,stream>>>(x, ln1g, ln1b, wk, wc, ck, mask, x1, wkcb, kbf);
  xgT_kernel<<<256,256,0,stream>>>(x1, xgT);

  // conv GEMM (stacked, 8-wave K-split): q (rows<512) + k_cur (rows>=512)
  gemm4<0,false,true,8><<<dim3(8,32),512,0,stream>>>(wkcb, xgT, nullptr, nullptr,
      nullptr, qbf, kbf + (size_t)65536*256, 512, 1024, 256, 1536);

  // attention partials + shadow weight transposes (blocks >= 1056)
  attn_flash<<<3232,128,0,stream>>>(qbf, kbf, mask, apw, fcw, pjw, apT, fcT, pjT, pO, pL);
  attn_reduce<<<512,256,0,stream>>>(pO, pL, mask, qbf, aoutb);

  // x2 = x1 + atten@ap_w + ap_b
  gemm4<0,true,false,4><<<dim3(16,16),256,0,stream>>>(aoutb, apT, apb, x1,
      x2, nullptr, nullptr, 512, 512, 512, 256);
  ln_kernel<true><<<512,256,0,stream>>>(x2, ln2g, ln2b, nullptr, x2nb);
  // h = swish(x2n@fc_w + fc_b)
  gemm4<1,false,true,4><<<dim3(64,16),256,0,stream>>>(x2nb, fcT, fcb, nullptr,
      nullptr, hb, hb, 4096, 512, 2048, 512);
  // out = x2 + h@proj_w + proj_b
  gemm4<0,true,false,8><<<dim3(16,16),512,0,stream>>>(hb, pjT, pjb, x2,
      out, nullptr, nullptr, 512, 512, 512, 2048);
}

// Round 20
// 112.484 us; speedup vs baseline: 1.1042x; 1.0036x over previous
//
#include <hip/hip_runtime.h>
#include <hip/hip_bf16.h>

typedef unsigned short u16;
typedef unsigned int u32;
typedef __attribute__((ext_vector_type(8))) short bf16x8;
typedef __attribute__((ext_vector_type(4))) short bf16x4;
typedef __attribute__((ext_vector_type(4))) float f32x4;
typedef __attribute__((ext_vector_type(8))) u16 u16x8;
typedef __attribute__((ext_vector_type(4))) u16 u16x4;
typedef __attribute__((ext_vector_type(4))) u32 u32x4;

__device__ __forceinline__ u16 f2bf(float x){
  __hip_bfloat16 h = __float2bfloat16(x);
  return __builtin_bit_cast(u16, h);
}
__device__ __forceinline__ float bf2f(u16 u){
  __hip_bfloat16 h = __builtin_bit_cast(__hip_bfloat16, u);
  return __bfloat162float(h);
}

// ---------------- LayerNorm over rows of 512 (used for ln2 only) ----------------
template<bool BF>
__global__ __launch_bounds__(256) void ln_kernel(const float* __restrict__ in,
    const float* __restrict__ g, const float* __restrict__ b,
    float* __restrict__ outf, u16* __restrict__ outb)
{
  int row = blockIdx.x, tid = threadIdx.x;
  const float* p = in + (size_t)row*512 + tid*2;
  float v0 = p[0], v1 = p[1];
  float s = v0+v1, ss = v0*v0+v1*v1;
  #pragma unroll
  for (int o=1;o<64;o<<=1){ s += __shfl_xor(s,o); ss += __shfl_xor(ss,o); }
  __shared__ float rs[4], rss[4];
  if ((tid&63)==0){ rs[tid>>6]=s; rss[tid>>6]=ss; }
  __syncthreads();
  s = rs[0]+rs[1]+rs[2]+rs[3]; ss = rss[0]+rss[1]+rss[2]+rss[3];
  float mean = s*(1.f/512.f);
  float var  = ss*(1.f/512.f) - mean*mean;
  float rstd = 1.f/sqrtf(var + 1e-5f);
  int d = tid*2;
  float o0 = (v0-mean)*rstd*g[d]   + b[d];
  float o1 = (v1-mean)*rstd*g[d+1] + b[d+1];
  if (BF){
    outb[(size_t)row*512+d]   = f2bf(o0);
    outb[(size_t)row*512+d+1] = f2bf(o1);
  } else {
    outf[(size_t)row*512+d]   = o0;
    outf[(size_t)row*512+d+1] = o1;
  }
}

// ---------------- conv input gather (transposed, bf16) ----------------
__global__ __launch_bounds__(256) void xgT_kernel(const float* __restrict__ x1, u16* __restrict__ xgT)
{
  int h = blockIdx.x, tid = threadIdx.x;
  #pragma unroll
  for (int rep=0;rep<6;rep++){
    int k = rep*256 + tid;
    int i = k/3, kk = k - i*3;
    int pos = 2*h - 1 + kk;
    float v = (pos >= 0 && pos < 512) ? x1[(size_t)i*512 + pos] : 0.f;
    xgT[(size_t)h*1536 + k] = f2bf(v);
  }
}

// ---------------- transpose+convert body, 128-thread variant ----------------
__device__ __forceinline__ void transcvt128(float (*t)[33],
    const float* __restrict__ in, u16* __restrict__ out, int K, int N, int bx, int by)
{
  int nb = bx*32, kb = by*32;
  int tx = threadIdx.x & 31, ty = threadIdx.x >> 5;   // ty 0..3
  #pragma unroll
  for (int i=0;i<32;i+=4) t[ty+i][tx] = in[(size_t)(kb+ty+i)*N + nb+tx];
  __syncthreads();
  #pragma unroll
  for (int i=0;i<32;i+=4) out[(size_t)(nb+ty+i)*K + kb+tx] = f2bf(t[tx][ty+i]);
}

// ---------------- prep1: ln1 + wk/wc cvt ----------------
// partition: [0,512) ln1 | [512,1280) wkcb
__global__ __launch_bounds__(256) void prep_kernel(
    const float* __restrict__ x, const float* __restrict__ ln1g, const float* __restrict__ ln1b,
    const float* __restrict__ wk, const float* __restrict__ wc,
    float* __restrict__ x1, u16* __restrict__ wkcb)
{
  __shared__ float rs[4], rss[4];
  int b = blockIdx.x, tid = threadIdx.x;
  if (b < 512){                       // ln1: x -> x1 (f32)
    const float* p = x + (size_t)b*512 + tid*2;
    float v0 = p[0], v1 = p[1];
    float s = v0+v1, ss = v0*v0+v1*v1;
    #pragma unroll
    for (int o=1;o<64;o<<=1){ s += __shfl_xor(s,o); ss += __shfl_xor(ss,o); }
    if ((tid&63)==0){ rs[tid>>6]=s; rss[tid>>6]=ss; }
    __syncthreads();
    s = rs[0]+rs[1]+rs[2]+rs[3]; ss = rss[0]+rss[1]+rss[2]+rss[3];
    float mean = s*(1.f/512.f);
    float var  = ss*(1.f/512.f) - mean*mean;
    float rstd = 1.f/sqrtf(var + 1e-5f);
    int d = tid*2;
    x1[(size_t)b*512+d]   = (v0-mean)*rstd*ln1g[d]   + ln1b[d];
    x1[(size_t)b*512+d+1] = (v0=v1,(v1-mean))*rstd*ln1g[d+1] + ln1b[d+1];
  } else {                            // wk|wc -> wkcb (stacked 1024x1536)
    size_t i = (size_t)((b-512)*256 + tid)*8;
    const size_t half = (size_t)512*1536;
    const float* src = (i < half) ? (wk + i) : (wc + (i - half));
    u16x8 o;
    #pragma unroll
    for (int j=0;j<8;j++) o[j] = f2bf(src[j]);
    *(u16x8*)(wkcb + i) = o;
  }
}

// ---------------- fused conv GEMM + cached_k cvt (512 thr) ----------------
// blocks [0,256): conv GEMM 8-wave K-split, m0=(bid>>3)*32, n0=(bid&7)*32
//   (A=wkcb 1024x1536, B=xgT 256x1536; rows<512 -> qbf, rows>=512 -> kbf tail)
// blocks [256,4352): cached_k -> bf16, 16 rows/block (t-block-uniform mask gate)
__global__ __launch_bounds__(512) void conv_cvt(
    const u16* __restrict__ wkcb, const u16* __restrict__ xgT,
    const float* __restrict__ ck, const int* __restrict__ mask,
    u16* __restrict__ qbf, u16* __restrict__ kbf)
{
  __shared__ float red[8][32][33];
  int bid = blockIdx.x, tid = threadIdx.x;
  if (bid >= 256){                    // ---- cached cvt (BW shadow host) ----
    int flat = (bid-256)*512 + tid;   // 16 rows per block, same t-block
    int row = flat >> 5, seg = flat & 31;
    if (mask[row>>9] == 0) return;
    const float* src = ck + (size_t)row*256 + seg*8;
    u16x8 o;
    #pragma unroll
    for (int j=0;j<8;j++) o[j] = f2bf(src[j]);
    *(u16x8*)(kbf + (size_t)row*256 + seg*8) = o;
    return;
  }
  // ---- conv GEMM block ----
  const int M = 1024, N = 256, K = 1536, rowSplit = 512;
  int w = tid >> 6, lane = tid & 63;
  int lq = lane & 15, lg = lane >> 4;
  int m0 = (bid >> 3)*32, n0 = (bid & 7)*32;
  int Ks = K >> 3;
  int kbeg = w * Ks;
  f32x4 acc00={0,0,0,0}, acc01={0,0,0,0}, acc10={0,0,0,0}, acc11={0,0,0,0};
  const u16* pa0 = wkcb + (size_t)(m0+lq)*K + kbeg + lg*8;
  const u16* pa1 = pa0 + (size_t)16*K;
  const u16* pb0 = xgT + (size_t)(n0+lq)*K + kbeg + lg*8;
  const u16* pb1 = pb0 + (size_t)16*K;
  #pragma unroll 2
  for (int k0=0;k0<Ks;k0+=32){
    bf16x8 a0 = *(const bf16x8*)(pa0+k0);
    bf16x8 a1 = *(const bf16x8*)(pa1+k0);
    bf16x8 b0 = *(const bf16x8*)(pb0+k0);
    bf16x8 b1 = *(const bf16x8*)(pb1+k0);
    acc00 = __builtin_amdgcn_mfma_f32_16x16x32_bf16(a0,b0,acc00,0,0,0);
    acc01 = __builtin_amdgcn_mfma_f32_16x16x32_bf16(a0,b1,acc01,0,0,0);
    acc10 = __builtin_amdgcn_mfma_f32_16x16x32_bf16(a1,b0,acc10,0,0,0);
    acc11 = __builtin_amdgcn_mfma_f32_16x16x32_bf16(a1,b1,acc11,0,0,0);
  }
  f32x4 accs[2][2] = {{acc00,acc01},{acc10,acc11}};
  #pragma unroll
  for (int mi=0;mi<2;mi++)
    #pragma unroll
    for (int ni=0;ni<2;ni++)
      #pragma unroll
      for (int r=0;r<4;r++)
        red[w][mi*16+lg*4+r][ni*16+lq] = accs[mi][ni][r];
  __syncthreads();
  #pragma unroll
  for (int rr=0;rr<2;rr++){
    int cell = rr*512 + tid;
    int row = cell >> 5, col = cell & 31;
    float v = 0.f;
    #pragma unroll
    for (int ww=0;ww<8;ww++) v += red[ww][row][col];
    int grow = m0 + row, gcol = n0 + col;
    if (grow < rowSplit) qbf[(size_t)grow*N+gcol] = f2bf(v);
    else                 kbf[(size_t)(65536 + grow-rowSplit)*N+gcol] = f2bf(v);
  }
}

// ---------------- bf16 MFMA GEMM, W-wave K-split: 32x32 tile ----------------
template<int ACT, bool WF32, bool WBF, int W>
__global__ __launch_bounds__(64*W) void gemm4(
    const u16* __restrict__ A, const u16* __restrict__ B,
    const float* __restrict__ bias, const float* __restrict__ resid,
    float* __restrict__ outF, u16* __restrict__ outB, u16* __restrict__ outB2,
    int rowSplit, int M, int N, int K)
{
  __shared__ float red[W][32][33];
  int tid = threadIdx.x;
  int w = tid >> 6, lane = tid & 63;
  int lq = lane & 15, lg = lane >> 4;
  int m0 = blockIdx.y*32, n0 = blockIdx.x*32;
  int Ks = K / W;
  int kbeg = w * Ks;
  f32x4 acc00={0,0,0,0}, acc01={0,0,0,0}, acc10={0,0,0,0}, acc11={0,0,0,0};
  const u16* pa0 = A + (size_t)(m0+lq)*K + kbeg + lg*8;
  const u16* pa1 = pa0 + (size_t)16*K;
  const u16* pb0 = B + (size_t)(n0+lq)*K + kbeg + lg*8;
  const u16* pb1 = pb0 + (size_t)16*K;
  #pragma unroll 2
  for (int k0=0;k0<Ks;k0+=32){
    bf16x8 a0 = *(const bf16x8*)(pa0+k0);
    bf16x8 a1 = *(const bf16x8*)(pa1+k0);
    bf16x8 b0 = *(const bf16x8*)(pb0+k0);
    bf16x8 b1 = *(const bf16x8*)(pb1+k0);
    acc00 = __builtin_amdgcn_mfma_f32_16x16x32_bf16(a0,b0,acc00,0,0,0);
    acc01 = __builtin_amdgcn_mfma_f32_16x16x32_bf16(a0,b1,acc01,0,0,0);
    acc10 = __builtin_amdgcn_mfma_f32_16x16x32_bf16(a1,b0,acc10,0,0,0);
    acc11 = __builtin_amdgcn_mfma_f32_16x16x32_bf16(a1,b1,acc11,0,0,0);
  }
  f32x4 accs[2][2] = {{acc00,acc01},{acc10,acc11}};
  #pragma unroll
  for (int mi=0;mi<2;mi++)
    #pragma unroll
    for (int ni=0;ni<2;ni++)
      #pragma unroll
      for (int r=0;r<4;r++)
        red[w][mi*16+lg*4+r][ni*16+lq] = accs[mi][ni][r];
  __syncthreads();
  #pragma unroll
  for (int rr=0;rr<16/W;rr++){
    int cell = rr*64*W + tid;        // 0..1023
    int row = cell >> 5, col = cell & 31;
    float v = 0.f;
    #pragma unroll
    for (int ww=0;ww<W;ww++) v += red[ww][row][col];
    int grow = m0 + row, gcol = n0 + col;
    if (bias)  v += bias[gcol];
    if (ACT==1) v = v/(1.f+__expf(-1.702f*v));
    if (resid) v += resid[(size_t)grow*N+gcol];
    if (WF32) outF[(size_t)grow*N+gcol] = v;
    if (WBF){
      if (grow < rowSplit) outB[(size_t)grow*N+gcol] = f2bf(v);
      else                 outB2[(size_t)(grow-rowSplit)*N+gcol] = f2bf(v);
    }
  }
}

// ---------------- flash attention (r13-verified core) + shadow weight transposes ----------------
// 1-D grid 3232: blocks [0,1056) = attention (c = bid%66, qt = bid/66);
// blocks [1056,3232) = apT/fcT/pjT transposes (occupancy shadow; LDS overlays kv).
__global__ __launch_bounds__(128) void attn_flash(
    const u16* __restrict__ qb, const u16* __restrict__ keys,
    const int* __restrict__ mask,
    const float* __restrict__ apw, const float* __restrict__ fcw, const float* __restrict__ pjw,
    u16* __restrict__ apT, u16* __restrict__ fcT, u16* __restrict__ pjT,
    u16* __restrict__ pO, float* __restrict__ pL)
{
  __shared__ u16 kv[2][8192];
  int tid = threadIdx.x;
  int bid = blockIdx.x;
  if (bid >= 1056){                   // ---- shadow transposes ----
    int f = bid - 1056;
    float (*t)[33] = reinterpret_cast<float(*)[33]>(&kv[0][0]);
    if (f < 128)       transcvt128(t, apw, apT, 256, 512, f & 15, f >> 4);
    else if (f < 1152) transcvt128(t, fcw, fcT, 512, 2048, (f-128) & 63, (f-128) >> 6);
    else               transcvt128(t, pjw, pjT, 2048, 512, (f-1152) & 15, (f-1152) >> 4);
    return;
  }
  int w = tid >> 6, lane = tid & 63, lq = lane & 15, lg = lane >> 4;
  int c = bid % 66, qt = bid / 66;
  const u16* kp = keys;
  int kstart = c * 1024, off = 0, nt = 32;
  if (c == 65) { kp = qb; kstart = 0; nt = 16; }
  else if (c == 64) { kstart = 65536; nt = 16; }
  else {
    int m0 = mask[2*c], m1 = mask[2*c+1];
    if (!m0 && !m1) return;
    off = m0 ? 0 : 512;
    nt = ((m0 && m1) ? 32 : 16);
  }
  int qbase = qt*32 + w*16;

  bf16x8 qf[8];
  {
    const u16* qrow = qb + (size_t)(qbase+lq)*256 + lg*8;
    #pragma unroll
    for (int s=0;s<8;s++) qf[s] = *(const bf16x8*)(qrow + s*32);
  }
  f32x4 o[16];
  #pragma unroll
  for (int i=0;i<16;i++) o[i] = (f32x4){0,0,0,0};
  float l_acc = 0.f;

  auto kv3 = (__attribute__((address_space(3))) char*)&kv[0][0];
  unsigned kvaddr0 = (unsigned)(unsigned long long)kv3;
  const char* gbase = (const char*)kp + (size_t)(kstart+off)*512;

  #define STAGE(i, b) { \
    const char* tb = gbase + (size_t)(i)*16384; \
    _Pragma("unroll") \
    for (int rep=0; rep<8; rep++){ \
      int slot = rep*128 + tid; \
      int goff = ((slot&63)>>1)*512 + ((slot>>6)*16 + (slot&1)*8)*2; \
      __builtin_amdgcn_global_load_lds( \
        (const __attribute__((address_space(1))) unsigned*)(tb + goff), \
        (__attribute__((address_space(3))) unsigned*)(kv3 + (b)*16384 + (rep*128 + (tid & ~63))*16), \
        16, 0, 0); \
    } }

  #define ISSUE8(T, ab) \
    asm volatile( \
      "ds_read_b64_tr_b16 %0, %8 offset:0\n\t" \
      "ds_read_b64_tr_b16 %1, %8 offset:512\n\t" \
      "ds_read_b64_tr_b16 %2, %8 offset:1024\n\t" \
      "ds_read_b64_tr_b16 %3, %8 offset:1536\n\t" \
      "ds_read_b64_tr_b16 %4, %8 offset:2048\n\t" \
      "ds_read_b64_tr_b16 %5, %8 offset:2560\n\t" \
      "ds_read_b64_tr_b16 %6, %8 offset:3072\n\t" \
      "ds_read_b64_tr_b16 %7, %8 offset:3584\n\t" \
      : "=&v"(T[0]),"=&v"(T[1]),"=&v"(T[2]),"=&v"(T[3]), \
        "=&v"(T[4]),"=&v"(T[5]),"=&v"(T[6]),"=&v"(T[7]) \
      : "v"(ab) : "memory")

  #define MFMA4(T, base) { \
    bf16x8 v0_ = __builtin_shufflevector(T[0],T[1],0,1,2,3,4,5,6,7); \
    bf16x8 v1_ = __builtin_shufflevector(T[2],T[3],0,1,2,3,4,5,6,7); \
    bf16x8 v2_ = __builtin_shufflevector(T[4],T[5],0,1,2,3,4,5,6,7); \
    bf16x8 v3_ = __builtin_shufflevector(T[6],T[7],0,1,2,3,4,5,6,7); \
    o[(base)+0] = __builtin_amdgcn_mfma_f32_16x16x32_bf16(pa, v0_, o[(base)+0], 0,0,0); \
    o[(base)+1] = __builtin_amdgcn_mfma_f32_16x16x32_bf16(pa, v1_, o[(base)+1], 0,0,0); \
    o[(base)+2] = __builtin_amdgcn_mfma_f32_16x16x32_bf16(pa, v2_, o[(base)+2], 0,0,0); \
    o[(base)+3] = __builtin_amdgcn_mfma_f32_16x16x32_bf16(pa, v3_, o[(base)+3], 0,0,0); \
  }

  STAGE(0, 0);
  for (int i=0; i<nt; i++){
    int cur = i & 1;
    if (i+1 < nt){
      STAGE(i+1, cur^1);
      asm volatile("s_waitcnt vmcnt(8)" ::: "memory");
    } else {
      asm volatile("s_waitcnt vmcnt(0)" ::: "memory");
    }
    __syncthreads();

    // ---- QK^T (S^T = K * Q^T), A-frags as b128 from subtiled LDS ----
    const u16* kb = &kv[cur][0];
    f32x4 s0 = {0,0,0,0}, s1 = {0,0,0,0};
    #pragma unroll
    for (int s=0;s<8;s++){
      int e = (2*s + (lg>>1))*512 + lq*16 + (lg&1)*8;
      bf16x8 ka0 = *(const bf16x8*)(kb + e);
      bf16x8 ka1 = *(const bf16x8*)(kb + e + 256);
      s0 = __builtin_amdgcn_mfma_f32_16x16x32_bf16(ka0, qf[s], s0, 0,0,0);
      s1 = __builtin_amdgcn_mfma_f32_16x16x32_bf16(ka1, qf[s], s1, 0,0,0);
    }
    asm volatile("s_waitcnt lgkmcnt(0)" ::: "memory");

    // ---- PV tr_reads: issue two groups ahead, overlap exp/pack with latency ----
    unsigned trb = kvaddr0 + cur*16384 + lane*8;
    bf16x4 tA[8], tB[8], tC[8], tD[8];
    ISSUE8(tA, trb);
    ISSUE8(tB, trb + 4096);

    // ---- exp (no max); lane holds q=lq, keys {4lg+r} and {16+4lg+r} ----
    float p[8];
    #pragma unroll
    for (int r=0;r<4;r++){ p[r]   = __expf(s0[r]*0.0625f);
                           p[4+r] = __expf(s1[r]*0.0625f); }
    l_acc += (p[0]+p[1])+(p[2]+p[3])+((p[4]+p[5])+(p[6]+p[7]));
    // A-frag = own p values (k-perm: position j <-> key {4lg+j, 16+4lg+(j-4)})
    u32 w0 = (u32)f2bf(p[0]) | ((u32)f2bf(p[1])<<16);
    u32 w1 = (u32)f2bf(p[2]) | ((u32)f2bf(p[3])<<16);
    u32 w2 = (u32)f2bf(p[4]) | ((u32)f2bf(p[5])<<16);
    u32 w3 = (u32)f2bf(p[6]) | ((u32)f2bf(p[7])<<16);
    u32x4 fq = {w0,w1,w2,w3};
    bf16x8 pa = __builtin_bit_cast(bf16x8, fq);

    // ---- counted-wait pipeline ----
    asm volatile("s_waitcnt lgkmcnt(8)" ::: "memory");
    __builtin_amdgcn_sched_barrier(0);
    MFMA4(tA, 0);
    ISSUE8(tC, trb + 8192);
    asm volatile("s_waitcnt lgkmcnt(8)" ::: "memory");
    __builtin_amdgcn_sched_barrier(0);
    MFMA4(tB, 4);
    ISSUE8(tD, trb + 12288);
    asm volatile("s_waitcnt lgkmcnt(8)" ::: "memory");
    __builtin_amdgcn_sched_barrier(0);
    MFMA4(tC, 8);
    asm volatile("s_waitcnt lgkmcnt(0)" ::: "memory");
    __builtin_amdgcn_sched_barrier(0);
    MFMA4(tD, 12);
    __syncthreads();
  }
  #undef STAGE
  #undef ISSUE8
  #undef MFMA4

  l_acc += __shfl_xor(l_acc, 16);
  l_acc += __shfl_xor(l_acc, 32);
  size_t qrow = (size_t)c*512 + qbase;
  if (lane < 16) pL[qrow + lq] = l_acc;
  // o[dt][r] = O[q = 4lg+r][d = dt*16+lq]
  #pragma unroll
  for (int dt=0; dt<16; dt++){
    #pragma unroll
    for (int r=0;r<4;r++){
      pO[(qrow + lg*4 + r)*256 + dt*16 + lq] = f2bf(o[dt][r]);
    }
  }
}

// ---------------- combine (vectorized): plain sums + masked count + self + 1.5*q ----------------
__global__ __launch_bounds__(256) void attn_reduce(
    const u16* __restrict__ pO, const float* __restrict__ pL,
    const int* __restrict__ mask, const u16* __restrict__ qb,
    u16* __restrict__ attn_out)
{
  __shared__ f32x4 redO[4][64];
  __shared__ float redL[4];
  __shared__ float scnt[2];
  int q = blockIdx.x, tid = threadIdx.x;
  int cg = tid >> 6, dq = tid & 63;

  float mz = (tid < 128) ? ((mask[tid]==0) ? 1.f : 0.f) : 0.f;
  #pragma unroll
  for (int o=1;o<64;o<<=1) mz += __shfl_xor(mz, o);
  if ((tid&63)==0 && tid < 128) scnt[tid>>6] = mz;

  f32x4 acc = {0,0,0,0};
  float lsum = 0.f;
  for (int c = cg; c < 65; c += 4){
    bool valid = (c==64) || mask[2*c] || mask[2*c+1];
    if (!valid) continue;
    u16x4 v = *(const u16x4*)(pO + ((size_t)c*512+q)*256 + dq*4);
    acc[0] += bf2f(v[0]); acc[1] += bf2f(v[1]);
    acc[2] += bf2f(v[2]); acc[3] += bf2f(v[3]);
    if (dq==0) lsum += pL[(size_t)c*512+q];
  }
  redO[cg][dq] = acc;
  if (dq==0) redL[cg] = lsum;
  __syncthreads();
  if (tid < 64){
    f32x4 s = redO[0][tid];
    f32x4 s1 = redO[1][tid], s2 = redO[2][tid], s3 = redO[3][tid];
    s[0]+=s1[0]+s2[0]+s3[0]; s[1]+=s1[1]+s2[1]+s3[1];
    s[2]+=s1[2]+s2[2]+s3[2]; s[3]+=s1[3]+s2[3]+s3[3];
    float den = redL[0]+redL[1]+redL[2]+redL[3] + 512.f*(scnt[0]+scnt[1]);
    float ls  = pL[(size_t)65*512 + q];
    u16x4 sv = *(const u16x4*)(pO + ((size_t)65*512+q)*256 + tid*4);
    u16x4 qv = *(const u16x4*)(qb + (size_t)q*256 + tid*4);
    u16x4 ov;
    #pragma unroll
    for (int j=0;j<4;j++)
      ov[j] = f2bf(s[j]/den + 0.5f*bf2f(sv[j])/ls + 1.5f*bf2f(qv[j]));
    *(u16x4*)(attn_out + (size_t)q*256 + tid*4) = ov;
  }
}

extern "C" void kernel_launch(void* const* d_in, const int* in_sizes, int n_in,
                              void* d_out, int out_size, void* d_ws, size_t ws_size,
                              hipStream_t stream)
{
  const float* x    = (const float*)d_in[0];
  const float* ck   = (const float*)d_in[1];
  const float* ln1g = (const float*)d_in[2];
  const float* ln1b = (const float*)d_in[3];
  const float* ln2g = (const float*)d_in[4];
  const float* ln2b = (const float*)d_in[5];
  const float* wk   = (const float*)d_in[6];
  const float* wc   = (const float*)d_in[7];
  const float* apw  = (const float*)d_in[8];
  const float* apb  = (const float*)d_in[9];
  const float* fcw  = (const float*)d_in[10];
  const float* fcb  = (const float*)d_in[11];
  const float* pjw  = (const float*)d_in[12];
  const float* pjb  = (const float*)d_in[13];
  const int*   mask = (const int*)d_in[14];
  float* out = (float*)d_out;

  char* wsb = (char*)d_ws;
  float* x1    = (float*)(wsb + 0);          // 512x512 f32
  float* x2    = (float*)(wsb + 1048576);    // 512x512 f32
  u16*   aoutb = (u16*)  (wsb + 2097152);    // 512x256 bf16
  u16*   x2nb  = (u16*)  (wsb + 2359296);    // 512x512 bf16
  u16*   xgT   = (u16*)  (wsb + 2883584);    // 256x1536 bf16
  u16*   apT   = (u16*)  (wsb + 3670016);    // 512x256 bf16
  u16*   fcT   = (u16*)  (wsb + 3932160);    // 2048x512 bf16
  u16*   pjT   = (u16*)  (wsb + 6029312);    // 512x2048 bf16
  u16*   qbf   = (u16*)  (wsb + 8126464);    // 512x256 bf16
  u16*   kbf   = (u16*)  (wsb + 8388608);    // 66048x256 bf16 -> ends 42205184
  float* pL    = (float*)(wsb + 42205184);   // 66x512 f32
  u16*   pO    = (u16*)  (wsb + 42340352);   // 66x512x256 bf16 (ends 59641856)
  u16*   wkcb  = (u16*)  (wsb + 42340352);   // 1024x1536 bf16, aliases pO (conv runs before attn)
  u16*   hb    = (u16*)  (wsb + 42340352);   // 512x2048 bf16, aliases pO (used after reduce)

  // prep1 (ln1 + conv weights) -> xgT -> fused{conv gemm + cached cvt} -> attn(+shadow) -> reduce -> tail
  prep_kernel<<<1280,256,0,stream>>>(x, ln1g, ln1b, wk, wc, x1, wkcb);
  xgT_kernel<<<256,256,0,stream>>>(x1, xgT);
  conv_cvt<<<4352,512,0,stream>>>(wkcb, xgT, ck, mask, qbf, kbf);

  // attention partials + shadow weight transposes (blocks >= 1056)
  attn_flash<<<3232,128,0,stream>>>(qbf, kbf, mask, apw, fcw, pjw, apT, fcT, pjT, pO, pL);
  attn_reduce<<<512,256,0,stream>>>(pO, pL, mask, qbf, aoutb);

  // x2 = x1 + atten@ap_w + ap_b
  gemm4<0,true,false,4><<<dim3(16,16),256,0,stream>>>(aoutb, apT, apb, x1,
      x2, nullptr, nullptr, 512, 512, 512, 256);
  ln_kernel<true><<<512,256,0,stream>>>(x2, ln2g, ln2b, nullptr, x2nb);
  // h = swish(x2n@fc_w + fc_b)
  gemm4<1,false,true,4><<<dim3(64,16),256,0,stream>>>(x2nb, fcT, fcb, nullptr,
      nullptr, hb, hb, 4096, 512, 2048, 512);
  // out = x2 + h@proj_w + proj_b
  gemm4<0,true,false,8><<<dim3(16,16),512,0,stream>>>(hb, pjT, pjb, x2,
      out, nullptr, nullptr, 512, 512, 512, 2048);
}